// Round 3
// baseline (1687.520 us; speedup 1.0000x reference)
//
#include <hip/hip_runtime.h>
#include <hip/hip_bf16.h>
#include <math.h>

#define D_   512
#define H_   8
#define HD_  64
#define L_   6
#define FF_  2048
#define IN_  32
#define OUT_ 3
#define S_   512
#define B_   32
#define M_   (B_ * S_)   // 16384 token rows

typedef __attribute__((ext_vector_type(8))) short short8;
typedef __attribute__((ext_vector_type(4))) float floatx4;

// Branchless gelu: 0.5x(1+erf(x/sqrt2)), erf via A&S 7.1.26 (max err 1.5e-7).
__device__ __forceinline__ float gelu_f(float x) {
    const float ax = fabsf(x) * 0.70710678118654752f;
    const float t = __builtin_amdgcn_rcpf(fmaf(0.3275911f, ax, 1.0f));
    float p = fmaf(1.061405429f, t, -1.453152027f);
    p = fmaf(p, t, 1.421413741f);
    p = fmaf(p, t, -0.284496736f);
    p = fmaf(p, t, 0.254829592f);
    p = p * t;
    const float e = __expf(-ax * ax);
    const float er = copysignf(fmaf(-p, e, 1.0f), x);
    return 0.5f * x * (1.0f + er);
}
__device__ __forceinline__ float bf2f(unsigned short u) {
    union { unsigned int i; float f; } c; c.i = ((unsigned)u) << 16; return c.f;
}
__device__ __forceinline__ unsigned short f2bf(float v) {
    __hip_bfloat16 t = __float2bfloat16(v);
    return *(unsigned short*)&t;
}
__device__ __forceinline__ void async16(const void* g, void* l) {
    __builtin_amdgcn_global_load_lds(
        (const __attribute__((address_space(1))) unsigned int*)g,
        (__attribute__((address_space(3))) unsigned int*)l, 16, 0, 0);
}
// one K-half stage step: 2 async16 (row srow and srow + rows/2)
__device__ __forceinline__ void stage2(const short* g, char* d, long rs, int off2) {
    async16(g, d);
    async16(g + rs, d + off2);
}

// ---------------------------------------------------------------------------
// Swizzle (T2, verified round 2: conflicts 4.19M -> 1.05M):
//   read col-block  qa = (q ^ ((r>>1)&3)) * 8 shorts
//   stage col-block sc = ((tid&3) ^ ((tid>>3)&3)) * 8 shorts
// Involution pair: LDS[row][cb] holds global block cb ^ ((row>>1)&3); lane
// (r,q) reads block q ^ ((r>>1)&3) -> global block q (wm, i*16 are 0 mod 4).
// ---------------------------------------------------------------------------

// ---------------------------------------------------------------------------
// 256x256 8-wave 4-phase/K-tile MFMA GEMM (T3+T4+T5, counted vmcnt).
// ROUND 3: restored the round-1 per-phase pins (barrier -> lgkmcnt(0) ->
// sched_barrier(0) -> setprio/MFMA). Raw s_barrier has NO memory-fence
// semantics in LLVM; without the pinned lgkm wait the scheduler migrated
// ds_reads/waits across barriers (round-2: 62 -> 93 us regression).
// Swizzle stays at the round-2 fixed version.
// ---------------------------------------------------------------------------
#define MFMA_ROW(ai, accr)                                                    \
    accr[0] = __builtin_amdgcn_mfma_f32_16x16x32_bf16(ai, b[0], accr[0], 0, 0, 0); \
    accr[1] = __builtin_amdgcn_mfma_f32_16x16x32_bf16(ai, b[1], accr[1], 0, 0, 0); \
    accr[2] = __builtin_amdgcn_mfma_f32_16x16x32_bf16(ai, b[2], accr[2], 0, 0, 0); \
    accr[3] = __builtin_amdgcn_mfma_f32_16x16x32_bf16(ai, b[3], accr[3], 0, 0, 0);

#define MFMA_PHASE(B0)                                                        \
    __builtin_amdgcn_s_barrier();                                             \
    asm volatile("s_waitcnt lgkmcnt(0)" ::: "memory");                        \
    __builtin_amdgcn_sched_barrier(0);                                        \
    __builtin_amdgcn_s_setprio(1);                                            \
    MFMA_ROW(a[0], acc[B0 + 0])                                               \
    MFMA_ROW(a[1], acc[B0 + 1])                                               \
    MFMA_ROW(a[2], acc[B0 + 2])                                               \
    MFMA_ROW(a[3], acc[B0 + 3])                                               \
    __builtin_amdgcn_s_setprio(0);

template<int DO_GELU, int OUT_BF16, int ADD_RES>
__global__ __launch_bounds__(512, 2)
void gemm_mfma256_k(const __hip_bfloat16* __restrict__ A,
                    const __hip_bfloat16* __restrict__ WT,
                    const float* __restrict__ bias,
                    const float* __restrict__ R,
                    void* __restrict__ C,
                    int N, int K) {
    __shared__ __align__(16) char smem[131072];

    const int tid  = threadIdx.x;
    const int lane = tid & 63;
    const int wave = tid >> 6;

    // XCD-aware remap (bijective: nwg multiple of 8)
    const int Lid = blockIdx.y * gridDim.x + blockIdx.x;
    const int xcd = Lid & 7;
    const int idx = Lid >> 3;
    const int gx  = gridDim.x, gy8 = gridDim.y >> 3;
    const int m0 = (xcd * gy8 + idx / gx) * 256;
    const int n0 = (idx % gx) * 256;

    const int wm = (wave >> 2) * 128;     // 2 waves in M
    const int wn = (wave & 3) * 64;       // 4 waves in N
    const int r = lane & 15, q = lane >> 4;
    const int qa = (q ^ ((r >> 1) & 3)) * 8;   // T2-fixed de-swizzle

    // staging: thread t covers rows (t>>2) and (t>>2)+128, swizzled col-block
    const int srow = tid >> 2;
    const int sc = ((tid & 3) ^ ((tid >> 3) & 3)) * 8;
    const short* Ag = (const short*)A + (long)(m0 + srow) * K + sc;
    const short* Bg = (const short*)WT + (long)(n0 + srow) * K + sc;
    const long rs = (long)128 * K;        // +128 rows (shorts)

    floatx4 acc[8][4];
    #pragma unroll
    for (int i = 0; i < 8; i++)
        #pragma unroll
        for (int j = 0; j < 4; j++) acc[i][j] = (floatx4)0.f;

    const int NT = K >> 6;

    // prologue: tile 0 -> buf0, issue order [A-ks0, B-ks0, A-ks1, B-ks1]
    stage2(Ag,      smem         + tid * 16, rs, 8192);
    stage2(Bg,      smem + 32768 + tid * 16, rs, 8192);
    stage2(Ag + 32, smem + 16384 + tid * 16, rs, 8192);
    stage2(Bg + 32, smem + 49152 + tid * 16, rs, 8192);
    asm volatile("s_waitcnt vmcnt(4)" ::: "memory");  // A-ks0,B-ks0 landed
    __builtin_amdgcn_s_barrier();

    short8 a[4], b[4];
    for (int t = 0; t < NT; ++t) {
        const int cur = t & 1, nxt = cur ^ 1;
        const bool hn = (t + 1 < NT);
        const short* As = (const short*)(smem + cur * 65536);
        const short* Bs = (const short*)(smem + cur * 65536 + 32768);
        const short* Agt = Ag + (t + 1) * 64;
        const short* Bgt = Bg + (t + 1) * 64;
        char* Ad = smem + nxt * 65536;
        char* Bd = smem + nxt * 65536 + 32768;

        // ---- phase 1: ks=0, m-frags 0-3, all 4 B-frags ----
        #pragma unroll
        for (int i = 0; i < 4; i++)
            a[i] = *(const short8*)&As[(wm + i * 16 + r) * 32 + qa];
        #pragma unroll
        for (int j = 0; j < 4; j++)
            b[j] = *(const short8*)&Bs[(wn + j * 16 + r) * 32 + qa];
        if (hn) stage2(Agt, Ad + tid * 16, rs, 8192);          // A-ks0(t+1)
        MFMA_PHASE(0)
        __builtin_amdgcn_s_barrier();

        // ---- phase 2: ks=0, m-frags 4-7 (reuse b) ----
        #pragma unroll
        for (int i = 0; i < 4; i++)
            a[i] = *(const short8*)&As[(wm + 64 + i * 16 + r) * 32 + qa];
        if (hn) stage2(Bgt, Bd + tid * 16, rs, 8192);          // B-ks0(t+1)
        MFMA_PHASE(4)
        if (hn) asm volatile("s_waitcnt vmcnt(4)" ::: "memory"); // A/B-ks1(t) in
        else    asm volatile("s_waitcnt vmcnt(0)" ::: "memory"); // tail drain
        __builtin_amdgcn_s_barrier();

        // ---- phase 3: ks=1, m-frags 0-3, new B-frags ----
        #pragma unroll
        for (int i = 0; i < 4; i++)
            a[i] = *(const short8*)&As[8192 + (wm + i * 16 + r) * 32 + qa];
        #pragma unroll
        for (int j = 0; j < 4; j++)
            b[j] = *(const short8*)&Bs[8192 + (wn + j * 16 + r) * 32 + qa];
        if (hn) stage2(Agt + 32, Ad + 16384 + tid * 16, rs, 8192); // A-ks1(t+1)
        MFMA_PHASE(0)
        __builtin_amdgcn_s_barrier();

        // ---- phase 4: ks=1, m-frags 4-7 ----
        #pragma unroll
        for (int i = 0; i < 4; i++)
            a[i] = *(const short8*)&As[8192 + (wm + 64 + i * 16 + r) * 32 + qa];
        if (hn) stage2(Bgt + 32, Bd + 16384 + tid * 16, rs, 8192); // B-ks1(t+1)
        MFMA_PHASE(4)
        if (hn) asm volatile("s_waitcnt vmcnt(4)" ::: "memory"); // A/B-ks0(t+1) in
        __builtin_amdgcn_s_barrier();
    }

    // ---- epilogue: 4 chunks of 64 rows restaged through LDS, coalesced ----
    float* Ef = (float*)smem;
    const int erow = tid >> 3;       // 0..63
    const int ej = tid & 7;          // 0..7
    #pragma unroll
    for (int ch = 0; ch < 4; ch++) {
        __builtin_amdgcn_s_barrier();
        if ((wave >> 2) == (ch >> 1)) {
            #pragma unroll
            for (int mf2 = 0; mf2 < 4; mf2++) {
                const int mf = (ch & 1) * 4 + mf2;
                #pragma unroll
                for (int nf = 0; nf < 4; nf++)
                    #pragma unroll
                    for (int rg = 0; rg < 4; rg++)
                        Ef[(mf2 * 16 + q * 4 + rg) * 260 + wn + nf * 16 + r] =
                            acc[mf][nf][rg];
            }
        }
        __builtin_amdgcn_s_barrier();
        #pragma unroll
        for (int e = 0; e < 8; e++) {
            const int c4 = ej + e * 8;   // float4 column 0..63
            const long grow = (long)(m0 + ch * 64 + erow) * N + n0 + c4 * 4;
            const float4 v = *(const float4*)&Ef[erow * 260 + c4 * 4];
            const float4 bv = *(const float4*)&bias[n0 + c4 * 4];
            float o0 = v.x + bv.x, o1 = v.y + bv.y;
            float o2 = v.z + bv.z, o3 = v.w + bv.w;
            if (DO_GELU) {
                o0 = gelu_f(o0); o1 = gelu_f(o1);
                o2 = gelu_f(o2); o3 = gelu_f(o3);
            }
            if (ADD_RES) {
                const float4 rv = *(const float4*)&R[grow];
                o0 += rv.x; o1 += rv.y; o2 += rv.z; o3 += rv.w;
            }
            if (OUT_BF16) {
                ushort4 pk;
                pk.x = f2bf(o0); pk.y = f2bf(o1);
                pk.z = f2bf(o2); pk.w = f2bf(o3);
                *(ushort4*)((unsigned short*)C + grow) = pk;
            } else {
                *(float4*)((float*)C + grow) = make_float4(o0, o1, o2, o3);
            }
        }
    }
}

// ---------------------------------------------------------------------------
// bf16 MFMA GEMM 128x128, counted-vmcnt 2-body ledger (round-2 verified:
// ~190us total win across qkv/outproj/ff2 vs PIPE=1). UNCHANGED this round.
// 64KB LDS -> 2 blocks/CU. Per K-tile: bodyA{issue ks0(t+1):4; read ks0;
// 16 MFMA; vmcnt(4); barrier} bodyB{same for ks1}.
// ---------------------------------------------------------------------------
template<int DO_GELU, int OUT_BF16, int ADD_RES>
__global__ __launch_bounds__(256, 2)
void gemm_mfma_k(const __hip_bfloat16* __restrict__ A,
                 const __hip_bfloat16* __restrict__ WT,
                 const float* __restrict__ bias,
                 const float* __restrict__ R,
                 void* __restrict__ C,
                 int N, int K) {
    __shared__ __align__(16) char smem[65536];
    float* Ep = (float*)smem;

    const int tid  = threadIdx.x;
    const int lane = tid & 63;
    const int wave = tid >> 6;

    const int Lid = blockIdx.y * gridDim.x + blockIdx.x;
    const int xcd = Lid & 7;
    const int idx = Lid >> 3;
    const int gx  = gridDim.x, gy8 = gridDim.y >> 3;
    const int m0 = (xcd * gy8 + idx / gx) * 128;
    const int n0 = (idx % gx) * 128;

    const int wm = (wave >> 1) * 64, wn = (wave & 1) * 64;
    const int r = lane & 15, q = lane >> 4;
    const int qa = (q ^ ((r >> 1) & 3)) * 8;   // T2-fixed de-swizzle

    const int srow = tid >> 2;                 // 0..63
    const int sc = ((tid & 3) ^ ((tid >> 3) & 3)) * 8;
    const short* Ag = (const short*)A + (long)(m0 + srow) * K + sc;
    const short* Bg = (const short*)WT + (long)(n0 + srow) * K + sc;
    const long rs = (long)64 * K;              // +64 rows (shorts)

    floatx4 acc[4][4];
    #pragma unroll
    for (int i = 0; i < 4; i++)
        #pragma unroll
        for (int j = 0; j < 4; j++) acc[i][j] = (floatx4)0.f;

    const int NT = K >> 6;

    // buffer b at smem + b*32768: A [ks][128][32sh] at +0, B at +16384.
    // prologue: tile 0, order [A-ks0, B-ks0, A-ks1, B-ks1]
    stage2(Ag,      smem + 0     + tid * 16, rs, 4096);
    stage2(Bg,      smem + 16384 + tid * 16, rs, 4096);
    stage2(Ag + 32, smem + 8192  + tid * 16, rs, 4096);
    stage2(Bg + 32, smem + 24576 + tid * 16, rs, 4096);
    asm volatile("s_waitcnt vmcnt(4)" ::: "memory");  // ks0 landed
    __builtin_amdgcn_s_barrier();
    __builtin_amdgcn_sched_barrier(0);

    short8 a[4], b[4];
    for (int t = 0; t < NT; ++t) {
        const int cur = t & 1, nxt = cur ^ 1;
        const bool hn = (t + 1 < NT);
        const short* As = (const short*)(smem + cur * 32768);
        const short* Bs = (const short*)(smem + cur * 32768 + 16384);
        const short* Agt = Ag + (t + 1) * 64;
        const short* Bgt = Bg + (t + 1) * 64;
        char* Ad = smem + nxt * 32768;
        char* Bd = smem + nxt * 32768 + 16384;

        // ---- body A: ks0 ----
        if (hn) {
            stage2(Agt, Ad + tid * 16, rs, 4096);              // A-ks0(t+1)
            stage2(Bgt, Bd + tid * 16, rs, 4096);              // B-ks0(t+1)
        }
        #pragma unroll
        for (int i = 0; i < 4; i++)
            a[i] = *(const short8*)&As[(wm + i * 16 + r) * 32 + qa];
        #pragma unroll
        for (int j = 0; j < 4; j++)
            b[j] = *(const short8*)&Bs[(wn + j * 16 + r) * 32 + qa];
        #pragma unroll
        for (int i = 0; i < 4; i++)
            #pragma unroll
            for (int j = 0; j < 4; j++)
                acc[i][j] = __builtin_amdgcn_mfma_f32_16x16x32_bf16(
                    a[i], b[j], acc[i][j], 0, 0, 0);
        __builtin_amdgcn_sched_barrier(0);
        if (hn) asm volatile("s_waitcnt vmcnt(4)" ::: "memory"); // ks1(t) in
        else    asm volatile("s_waitcnt vmcnt(0)" ::: "memory");
        __builtin_amdgcn_s_barrier();
        __builtin_amdgcn_sched_barrier(0);

        // ---- body B: ks1 ----
        if (hn) {
            stage2(Agt + 32, Ad + 8192 + tid * 16, rs, 4096);  // A-ks1(t+1)
            stage2(Bgt + 32, Bd + 8192 + tid * 16, rs, 4096);  // B-ks1(t+1)
        }
        #pragma unroll
        for (int i = 0; i < 4; i++)
            a[i] = *(const short8*)&As[4096 + (wm + i * 16 + r) * 32 + qa];
        #pragma unroll
        for (int j = 0; j < 4; j++)
            b[j] = *(const short8*)&Bs[4096 + (wn + j * 16 + r) * 32 + qa];
        #pragma unroll
        for (int i = 0; i < 4; i++)
            #pragma unroll
            for (int j = 0; j < 4; j++)
                acc[i][j] = __builtin_amdgcn_mfma_f32_16x16x32_bf16(
                    a[i], b[j], acc[i][j], 0, 0, 0);
        __builtin_amdgcn_sched_barrier(0);
        if (hn) asm volatile("s_waitcnt vmcnt(4)" ::: "memory"); // ks0(t+1) in
        __builtin_amdgcn_s_barrier();
        __builtin_amdgcn_sched_barrier(0);
    }

    // ---- epilogue: restage through LDS, coalesced postprocess + store ----
    const int erow = tid >> 5;          // 0..7
    const int ecol = (tid & 31) * 4;    // 0..124, float4 granularity
    const float4 bvec = *(const float4*)&bias[n0 + ecol];

    #pragma unroll
    for (int pass = 0; pass < 2; pass++) {
        if (pass) __syncthreads();      // pass0 Ep reads done before overwrite
        if ((wave >> 1) == pass) {
            #pragma unroll
            for (int i = 0; i < 4; i++)
                #pragma unroll
                for (int j = 0; j < 4; j++)
                    #pragma unroll
                    for (int rg = 0; rg < 4; rg++)
                        Ep[(i * 16 + q * 4 + rg) * 132 + wn + j * 16 + r] =
                            acc[i][j][rg];
        }
        __syncthreads();
        #pragma unroll
        for (int it = 0; it < 8; it++) {
            const int row = it * 8 + erow;   // 0..63 within half-tile
            const long grow = (long)(m0 + pass * 64 + row) * N + n0 + ecol;
            const float4 v = *(const float4*)&Ep[row * 132 + ecol];
            float o0 = v.x + bvec.x, o1 = v.y + bvec.y;
            float o2 = v.z + bvec.z, o3 = v.w + bvec.w;
            if (DO_GELU) {
                o0 = gelu_f(o0); o1 = gelu_f(o1);
                o2 = gelu_f(o2); o3 = gelu_f(o3);
            }
            if (ADD_RES) {
                const float4 rv = *(const float4*)&R[grow];
                o0 += rv.x; o1 += rv.y; o2 += rv.z; o3 += rv.w;
            }
            if (OUT_BF16) {
                ushort4 pk;
                pk.x = f2bf(o0); pk.y = f2bf(o1);
                pk.z = f2bf(o2); pk.w = f2bf(o3);
                *(ushort4*)((unsigned short*)C + grow) = pk;
            } else {
                *(float4*)((float*)C + grow) = make_float4(o0, o1, o2, o3);
            }
        }
    }
}

// ---------------------------------------------------------------------------
// WT[l][n][k] = (bf16) W[l][k][n]
// ---------------------------------------------------------------------------
__global__ __launch_bounds__(256)
void transpose_cast_k(const float* __restrict__ W, __hip_bfloat16* __restrict__ WT,
                      int K, int N) {
    __shared__ float tile[32][33];
    const float* Wl = W + (long)blockIdx.z * K * N;
    __hip_bfloat16* WTl = WT + (long)blockIdx.z * K * N;
    const int n0 = blockIdx.x * 32, k0 = blockIdx.y * 32;
    const int tx = threadIdx.x & 31, ty = threadIdx.x >> 5;
    for (int rr = ty; rr < 32; rr += 8)
        tile[rr][tx] = Wl[(long)(k0 + rr) * N + n0 + tx];
    __syncthreads();
    for (int rr = ty; rr < 32; rr += 8)
        WTl[(long)(n0 + rr) * K + k0 + tx] = __float2bfloat16(tile[tx][rr]);
}

// ---------------------------------------------------------------------------
// fp32 tiled GEMM (in-proj only: M=16384, N=512, K=32)
// ---------------------------------------------------------------------------
template<int DO_GELU>
__global__ __launch_bounds__(256)
void gemm_bias_k(const float* __restrict__ A, long lda,
                 const float* __restrict__ W,
                 const float* __restrict__ bias,
                 float* __restrict__ C,
                 int M, int N, int K) {
    __shared__ float As[16][64];
    __shared__ float Ws[16][64];
    const int tx = threadIdx.x;
    const int ty = threadIdx.y;
    const int tid = ty * 16 + tx;
    const int m0 = blockIdx.y * 64;
    const int n0 = blockIdx.x * 64;
    float acc[4][4] = {};
    for (int k0 = 0; k0 < K; k0 += 16) {
        #pragma unroll
        for (int e = tid; e < 64 * 16; e += 256) {
            int m = e >> 4, k = e & 15;
            float v = 0.f;
            if (m0 + m < M) v = A[(long)(m0 + m) * lda + k0 + k];
            As[k][m] = v;
        }
        #pragma unroll
        for (int e = tid; e < 16 * 64; e += 256) {
            int k = e >> 6, n = e & 63;
            float v = 0.f;
            if (n0 + n < N) v = W[(long)(k0 + k) * N + n0 + n];
            Ws[k][n] = v;
        }
        __syncthreads();
        #pragma unroll
        for (int kk = 0; kk < 16; kk++) {
            float a[4], w[4];
            #pragma unroll
            for (int i = 0; i < 4; i++) a[i] = As[kk][ty * 4 + i];
            #pragma unroll
            for (int j = 0; j < 4; j++) w[j] = Ws[kk][tx * 4 + j];
            #pragma unroll
            for (int i = 0; i < 4; i++)
                #pragma unroll
                for (int j = 0; j < 4; j++)
                    acc[i][j] += a[i] * w[j];
        }
        __syncthreads();
    }
    #pragma unroll
    for (int i = 0; i < 4; i++) {
        int m = m0 + ty * 4 + i;
        if (m >= M) continue;
        #pragma unroll
        for (int j = 0; j < 4; j++) {
            int n = n0 + tx * 4 + j;
            if (n >= N) continue;
            float v = acc[i][j] + bias[n];
            if (DO_GELU) v = gelu_f(v);
            C[(long)m * N + n] = v;
        }
    }
}

// ---------------------------------------------------------------------------
// Wave-per-row LN: H/Hb = layernorm(X)*g+be. 4 rows per 256-thr block.
// ---------------------------------------------------------------------------
__global__ __launch_bounds__(256)
void ln_k(const float* __restrict__ X,
          const float* __restrict__ g,
          const float* __restrict__ be,
          float* __restrict__ H,
          __hip_bfloat16* __restrict__ Hb) {
    const int row = blockIdx.x * 4 + (threadIdx.x >> 6);
    const int lane = threadIdx.x & 63;
    const float* xp = X + (long)row * D_ + lane * 8;
    const float4 a = *(const float4*)xp;
    const float4 c = *(const float4*)(xp + 4);
    float s = a.x + a.y + a.z + a.w + c.x + c.y + c.z + c.w;
    #pragma unroll
    for (int off = 1; off < 64; off <<= 1) s += __shfl_xor(s, off);
    const float mu = s * (1.0f / D_);
    float d[8] = { a.x - mu, a.y - mu, a.z - mu, a.w - mu,
                   c.x - mu, c.y - mu, c.z - mu, c.w - mu };
    float ss = 0.f;
    #pragma unroll
    for (int e = 0; e < 8; e++) ss += d[e] * d[e];
    #pragma unroll
    for (int off = 1; off < 64; off <<= 1) ss += __shfl_xor(ss, off);
    const float inv = 1.0f / sqrtf(ss * (1.0f / D_) + 1e-5f);
    const float4 g0 = *(const float4*)(g + lane * 8);
    const float4 g1 = *(const float4*)(g + lane * 8 + 4);
    const float4 e0 = *(const float4*)(be + lane * 8);
    const float4 e1 = *(const float4*)(be + lane * 8 + 4);
    const float gv[8] = { g0.x, g0.y, g0.z, g0.w, g1.x, g1.y, g1.z, g1.w };
    const float ev[8] = { e0.x, e0.y, e0.z, e0.w, e1.x, e1.y, e1.z, e1.w };
    float o[8];
    short8 pk;
    #pragma unroll
    for (int e = 0; e < 8; e++) {
        o[e] = d[e] * inv * gv[e] + ev[e];
        pk[e] = (short)f2bf(o[e]);
    }
    float* hp = H + (long)row * D_ + lane * 8;
    *(float4*)hp = make_float4(o[0], o[1], o[2], o[3]);
    *(float4*)(hp + 4) = make_float4(o[4], o[5], o[6], o[7]);
    *(short8*)((unsigned short*)Hb + (long)row * D_ + lane * 8) = pk;
}

// ---------------------------------------------------------------------------
// h = gelu(layernorm(X)) + pe ; also bf16 copy hb  (runs once)
// ---------------------------------------------------------------------------
__global__ __launch_bounds__(256)
void ln_gelu_pos_k(const float* __restrict__ X,
                   const float* __restrict__ g,
                   const float* __restrict__ be,
                   float* __restrict__ Hout,
                   __hip_bfloat16* __restrict__ Hb) {
    const int row = blockIdx.x;
    const int s = row & (S_ - 1);
    const int t = threadIdx.x;
    const float* x = X + (long)row * D_;
    float v0 = x[t], v1 = x[t + 256];
    __shared__ float red[256];
    red[t] = v0 + v1;
    __syncthreads();
    for (int off = 128; off; off >>= 1) {
        if (t < off) red[t] += red[t + off];
        __syncthreads();
    }
    float mu = red[0] * (1.0f / D_);
    __syncthreads();
    float d0 = v0 - mu, d1 = v1 - mu;
    red[t] = d0 * d0 + d1 * d1;
    __syncthreads();
    for (int off = 128; off; off >>= 1) {
        if (t < off) red[t] += red[t + off];
        __syncthreads();
    }
    float var = red[0] * (1.0f / D_);
    float inv = 1.0f / sqrtf(var + 1e-5f);
    float o0 = gelu_f(d0 * inv * g[t] + be[t]);
    float o1 = gelu_f(d1 * inv * g[t + 256] + be[t + 256]);
    {
        int d = t, i = d >> 1;
        float dv = expf((float)(2 * i) * (-9.210340371976184f / 512.0f));
        float ang = (float)s * dv;
        o0 += (d & 1) ? cosf(ang) : sinf(ang);
    }
    {
        int d = t + 256, i = d >> 1;
        float dv = expf((float)(2 * i) * (-9.210340371976184f / 512.0f));
        float ang = (float)s * dv;
        o1 += (d & 1) ? cosf(ang) : sinf(ang);
    }
    Hout[(long)row * D_ + t] = o0;
    Hout[(long)row * D_ + t + 256] = o1;
    Hb[(long)row * D_ + t] = __float2bfloat16(o0);
    Hb[(long)row * D_ + t + 256] = __float2bfloat16(o1);
}

// ---------------------------------------------------------------------------
// MFMA flash attention (verified Round-4 structure, unchanged)
// ---------------------------------------------------------------------------
#define LDT 72
__global__ __launch_bounds__(256)
void attn_mfma_k(const __hip_bfloat16* __restrict__ qkv,
                 __hip_bfloat16* __restrict__ O) {
    const int qt = blockIdx.x;
    const int bh = blockIdx.y;
    const int b = bh >> 3, h = bh & (H_ - 1);
    const int tid = threadIdx.x;
    const int wave = tid >> 6, lane = tid & 63;
    const int ln = lane & 15, quad = lane >> 4;
    const int wm = wave * 32;
    const int i0 = qt * 128;

    __shared__ unsigned short Qs[128 * LDT];
    __shared__ unsigned short Ks[64 * LDT];
    __shared__ unsigned short Vt[64 * LDT];
    __shared__ unsigned short Ps[128 * LDT];
    __shared__ float stat[128];

    const unsigned short* base = (const unsigned short*)qkv + (long)b * S_ * (3 * D_);

    {
        const int r0 = tid >> 3, c0 = (tid & 7) * 8;
        #pragma unroll
        for (int i = 0; i < 4; i++) {
            const int rw = i * 32 + r0;
            *(short8*)&Qs[rw * LDT + c0] =
                *(const short8*)(base + (long)(i0 + rw) * (3 * D_) + h * HD_ + c0);
        }
    }

    float m_i[2] = { -INFINITY, -INFINITY };
    float l_i[2] = { 0.f, 0.f };
    floatx4 o_acc[2][4];
    #pragma unroll
    for (int i = 0; i < 2; i++)
        #pragma unroll
        for (int j = 0; j < 4; j++) o_acc[i][j] = (floatx4)0.f;

    const int kr = tid >> 2, kc = (tid & 3) * 16;
    const int vj = tid & 63, vc = (tid >> 6) * 16;

    const int ktmax = 2 * qt + 1;
    for (int kt = 0; kt <= ktmax; kt++) {
        const int j0 = kt * 64;
        {
            const unsigned short* kp = base + (long)(j0 + kr) * (3 * D_) + D_ + h * HD_ + kc;
            *(short8*)&Ks[kr * LDT + kc]     = *(const short8*)(kp);
            *(short8*)&Ks[kr * LDT + kc + 8] = *(const short8*)(kp + 8);
            const unsigned short* vp = base + (long)(j0 + vj) * (3 * D_) + 2 * D_ + h * HD_ + vc;
            short8 v0 = *(const short8*)(vp);
            short8 v1 = *(const short8*)(vp + 8);
            #pragma unroll
            for (int e = 0; e < 8; e++) {
                Vt[(vc + e) * LDT + vj]     = (unsigned short)v0[e];
                Vt[(vc + 8 + e) * LDT + vj] = (unsigned short)v1[e];
            }
        }
        __syncthreads();

        floatx4 sa[4][2];
        #pragma unroll
        for (int mt = 0; mt < 4; mt++)
            #pragma unroll
            for (int nt = 0; nt < 2; nt++) sa[mt][nt] = (floatx4)0.f;
        #pragma unroll
        for (int c = 0; c < 2; c++) {
            short8 kf[4], qf[2];
            #pragma unroll
            for (int mt = 0; mt < 4; mt++)
                kf[mt] = *(const short8*)&Ks[(mt * 16 + ln) * LDT + c * 32 + quad * 8];
            #pragma unroll
            for (int nt = 0; nt < 2; nt++)
                qf[nt] = *(const short8*)&Qs[(wm + nt * 16 + ln) * LDT + c * 32 + quad * 8];
            #pragma unroll
            for (int mt = 0; mt < 4; mt++)
                #pragma unroll
                for (int nt = 0; nt < 2; nt++)
                    sa[mt][nt] = __builtin_amdgcn_mfma_f32_16x16x32_bf16(
                        kf[mt], qf[nt], sa[mt][nt], 0, 0, 0);
        }

        const bool domask = (kt >= 2 * qt);
        #pragma unroll
        for (int nt = 0; nt < 2; nt++) {
            const int qg = i0 + wm + nt * 16 + ln;
            float mx = -INFINITY;
            #pragma unroll
            for (int mt = 0; mt < 4; mt++)
                #pragma unroll
                for (int rg = 0; rg < 4; rg++) {
                    float v = sa[mt][nt][rg] * 0.125f;
                    if (domask && (j0 + mt * 16 + quad * 4 + rg > qg)) v = -INFINITY;
                    sa[mt][nt][rg] = v;
                    mx = fmaxf(mx, v);
                }
            mx = fmaxf(mx, __shfl_xor(mx, 16));
            mx = fmaxf(mx, __shfl_xor(mx, 32));
            const float mn = fmaxf(m_i[nt], mx);
            const float alpha = __expf(m_i[nt] - mn);
            m_i[nt] = mn;
            float ls = 0.f;
            #pragma unroll
            for (int mt = 0; mt < 4; mt++) {
                ushort4 pk;
                float p0 = __expf(sa[mt][nt][0] - mn);
                float p1 = __expf(sa[mt][nt][1] - mn);
                float p2 = __expf(sa[mt][nt][2] - mn);
                float p3 = __expf(sa[mt][nt][3] - mn);
                ls += p0 + p1 + p2 + p3;
                pk.x = f2bf(p0); pk.y = f2bf(p1); pk.z = f2bf(p2); pk.w = f2bf(p3);
                *(ushort4*)&Ps[(wm + nt * 16 + ln) * LDT + mt * 16 + quad * 4] = pk;
            }
            ls += __shfl_xor(ls, 16);
            ls += __shfl_xor(ls, 32);
            l_i[nt] = l_i[nt] * alpha + ls;
            if (quad == 0) stat[wm + nt * 16 + ln] = alpha;
        }

        #pragma unroll
        for (int mt2 = 0; mt2 < 2; mt2++) {
            #pragma unroll
            for (int rg = 0; rg < 4; rg++) {
                const float a = stat[wm + mt2 * 16 + quad * 4 + rg];
                #pragma unroll
                for (int nt = 0; nt < 4; nt++) o_acc[mt2][nt][rg] *= a;
            }
        }

        #pragma unroll
        for (int c = 0; c < 2; c++) {
            short8 pf[2], vf[4];
            #pragma unroll
            for (int mt2 = 0; mt2 < 2; mt2++)
                pf[mt2] = *(const short8*)&Ps[(wm + mt2 * 16 + ln) * LDT + c * 32 + quad * 8];
            #pragma unroll
            for (int nt = 0; nt < 4; nt++)
                vf[nt] = *(const short8*)&Vt[(nt * 16 + ln) * LDT + c * 32 + quad * 8];
            #pragma unroll
            for (int mt2 = 0; mt2 < 2; mt2++)
                #pragma unroll
                for (int nt = 0; nt < 4; nt++)
                    o_acc[mt2][nt] = __builtin_amdgcn_mfma_f32_16x16x32_bf16(
                        pf[mt2], vf[nt], o_acc[mt2][nt], 0, 0, 0);
        }
        __syncthreads();
    }

    if (quad == 0) {
        stat[wm + ln]      = l_i[0];
        stat[wm + 16 + ln] = l_i[1];
    }
    unsigned short* Og = (unsigned short*)O;
    #pragma unroll
    for (int mt2 = 0; mt2 < 2; mt2++) {
        #pragma unroll
        for (int rg = 0; rg < 4; rg++) {
            const float linv = 1.0f / stat[wm + mt2 * 16 + quad * 4 + rg];
            const long row = (long)(b * S_ + i0 + wm + mt2 * 16 + quad * 4 + rg);
            #pragma unroll
            for (int nt = 0; nt < 4; nt++)
                Og[row * D_ + h * HD_ + nt * 16 + ln] =
                    f2bf(o_acc[mt2][nt][rg] * linv);
        }
    }
}

// ---------------------------------------------------------------------------
// Head kernels
// ---------------------------------------------------------------------------
__global__ __launch_bounds__(256)
void head1_k(const float* __restrict__ h, const float* __restrict__ w1,
             const float* __restrict__ b1, float* __restrict__ th) {
    __shared__ float hs[D_];
    const int b = blockIdx.x, n = threadIdx.x;
    const float* hr = h + (long)(b * S_ + S_ - 1) * D_;
    hs[n] = hr[n];
    hs[n + 256] = hr[n + 256];
    __syncthreads();
    float s = 0.f;
    #pragma unroll 8
    for (int k = 0; k < D_; k++) s += hs[k] * w1[(long)k * 256 + n];
    th[b * 256 + n] = gelu_f(s + b1[n]);
}

__global__ __launch_bounds__(64)
void head2_k(const float* __restrict__ th, const float* __restrict__ w2,
             const float* __restrict__ b2, float* __restrict__ out) {
    const int b = blockIdx.x, lane = threadIdx.x;
    const float* t = th + b * 256;
    float s0 = 0.f, s1 = 0.f, s2 = 0.f;
    #pragma unroll
    for (int e = 0; e < 4; e++) {
        const int k = lane * 4 + e;
        const float tv = t[k];
        s0 += tv * w2[k * 3 + 0];
        s1 += tv * w2[k * 3 + 1];
        s2 += tv * w2[k * 3 + 2];
    }
    #pragma unroll
    for (int off = 1; off < 64; off <<= 1) {
        s0 += __shfl_xor(s0, off);
        s1 += __shfl_xor(s1, off);
        s2 += __shfl_xor(s2, off);
    }
    if (lane == 0) {
        out[b * 3 + 0] = s0 + b2[0];
        out[b * 3 + 1] = s1 + b2[1];
        out[b * 3 + 2] = s2 + b2[2];
    }
}

// ---------------------------------------------------------------------------
extern "C" void kernel_launch(void* const* d_in, const int* in_sizes, int n_in,
                              void* d_out, int out_size, void* d_ws, size_t ws_size,
                              hipStream_t stream) {
    const float* x     = (const float*)d_in[0];
    const float* w_in  = (const float*)d_in[1];
    const float* b_in  = (const float*)d_in[2];
    const float* g_in  = (const float*)d_in[3];
    const float* be_in = (const float*)d_in[4];
    const float* w_qkv = (const float*)d_in[5];
    const float* b_qkv = (const float*)d_in[6];
    const float* w_out = (const float*)d_in[7];
    const float* b_out = (const float*)d_in[8];
    const float* g1    = (const float*)d_in[9];
    const float* be1   = (const float*)d_in[10];
    const float* w_ff1 = (const float*)d_in[11];
    const float* b_ff1 = (const float*)d_in[12];
    const float* w_ff2 = (const float*)d_in[13];
    const float* b_ff2 = (const float*)d_in[14];
    const float* g2    = (const float*)d_in[15];
    const float* be2   = (const float*)d_in[16];
    const float* w_h1  = (const float*)d_in[17];
    const float* b_h1  = (const float*)d_in[18];
    const float* w_h2  = (const float*)d_in[19];
    const float* b_h2  = (const float*)d_in[20];
    float* out = (float*)d_out;

    float* h    = (float*)d_ws;
    float* bufB = h + (long)M_ * D_;
    float* th   = bufB + (long)M_ * D_;
    __hip_bfloat16* hb    = (__hip_bfloat16*)(th + 32 * 256);
    __hip_bfloat16* attb  = hb + (long)M_ * D_;
    __hip_bfloat16* bufAb = attb + (long)M_ * D_;
    __hip_bfloat16* qkvT  = bufAb + (long)M_ * FF_;
    __hip_bfloat16* outT  = qkvT + (long)L_ * (3 * D_) * D_;
    __hip_bfloat16* ff1T  = outT + (long)L_ * D_ * D_;
    __hip_bfloat16* ff2T  = ff1T + (long)L_ * FF_ * D_;

    dim3 blk(16, 16);

    transpose_cast_k<<<dim3((3 * D_) / 32, D_ / 32, L_), 256, 0, stream>>>(w_qkv, qkvT, D_, 3 * D_);
    transpose_cast_k<<<dim3(D_ / 32, D_ / 32, L_), 256, 0, stream>>>(w_out, outT, D_, D_);
    transpose_cast_k<<<dim3(FF_ / 32, D_ / 32, L_), 256, 0, stream>>>(w_ff1, ff1T, D_, FF_);
    transpose_cast_k<<<dim3(D_ / 32, FF_ / 32, L_), 256, 0, stream>>>(w_ff2, ff2T, FF_, D_);

    gemm_bias_k<0><<<dim3(D_ / 64, M_ / 64), blk, 0, stream>>>(
        x, IN_, w_in, b_in, bufB, M_, D_, IN_);
    ln_gelu_pos_k<<<M_, 256, 0, stream>>>(bufB, g_in, be_in, h, hb);

    for (int l = 0; l < L_; l++) {
        // qkv -> bf16 bufAb (128^2 counted-vmcnt, 1536 blocks = 3 clean rounds)
        gemm_mfma_k<0, 1, 0><<<dim3((3 * D_) / 128, M_ / 128), 256, 0, stream>>>(
            hb, qkvT + (long)l * (3 * D_) * D_, b_qkv + l * 3 * D_, nullptr,
            bufAb, 3 * D_, D_);
        attn_mfma_k<<<dim3(S_ / 128, B_ * H_), 256, 0, stream>>>(bufAb, attb);
        // out-proj + residual(h) -> fp32 bufB ; h = LN(bufB)
        gemm_mfma_k<0, 0, 1><<<dim3(D_ / 128, M_ / 128), 256, 0, stream>>>(
            attb, outT + (long)l * D_ * D_, b_out + l * D_, h,
            bufB, D_, D_);
        ln_k<<<M_ / 4, 256, 0, stream>>>(bufB, g1 + l * D_, be1 + l * D_, h, hb);
        // ff1 -> bf16 bufAb (gelu)  (256^2 4-phase pinned, 512 blocks)
        gemm_mfma256_k<1, 1, 0><<<dim3(FF_ / 256, M_ / 256), 512, 0, stream>>>(
            hb, ff1T + (long)l * FF_ * D_, b_ff1 + l * FF_, nullptr,
            bufAb, FF_, D_);
        // ff2 + residual(h) -> fp32 bufB ; h = LN(bufB)
        gemm_mfma_k<0, 0, 1><<<dim3(D_ / 128, M_ / 128), 256, 0, stream>>>(
            bufAb, ff2T + (long)l * D_ * FF_, b_ff2 + l * D_, h,
            bufB, D_, FF_);
        ln_k<<<M_ / 4, 256, 0, stream>>>(bufB, g2 + l * D_, be2 + l * D_, h, hb);
    }

    head1_k<<<B_, 256, 0, stream>>>(h, w_h1, b_h1, th);
    head2_k<<<B_, 64, 0, stream>>>(th, w_h2, b_h2, out);
}

// Round 5
// 1638.014 us; speedup vs baseline: 1.0302x; 1.0302x over previous
//
#include <hip/hip_runtime.h>
#include <hip/hip_bf16.h>
#include <math.h>

#define D_   512
#define H_   8
#define HD_  64
#define L_   6
#define FF_  2048
#define IN_  32
#define OUT_ 3
#define S_   512
#define B_   32
#define M_   (B_ * S_)   // 16384 token rows

typedef __attribute__((ext_vector_type(8))) short short8;
typedef __attribute__((ext_vector_type(4))) float floatx4;

// Branchless gelu: 0.5x(1+erf(x/sqrt2)), erf via A&S 7.1.26 (max err 1.5e-7).
__device__ __forceinline__ float gelu_f(float x) {
    const float ax = fabsf(x) * 0.70710678118654752f;
    const float t = __builtin_amdgcn_rcpf(fmaf(0.3275911f, ax, 1.0f));
    float p = fmaf(1.061405429f, t, -1.453152027f);
    p = fmaf(p, t, 1.421413741f);
    p = fmaf(p, t, -0.284496736f);
    p = fmaf(p, t, 0.254829592f);
    p = p * t;
    const float e = __expf(-ax * ax);
    const float er = copysignf(fmaf(-p, e, 1.0f), x);
    return 0.5f * x * (1.0f + er);
}
__device__ __forceinline__ float bf2f(unsigned short u) {
    union { unsigned int i; float f; } c; c.i = ((unsigned)u) << 16; return c.f;
}
__device__ __forceinline__ unsigned short f2bf(float v) {
    __hip_bfloat16 t = __float2bfloat16(v);
    return *(unsigned short*)&t;
}
__device__ __forceinline__ void async16(const void* g, void* l) {
    __builtin_amdgcn_global_load_lds(
        (const __attribute__((address_space(1))) unsigned int*)g,
        (__attribute__((address_space(3))) unsigned int*)l, 16, 0, 0);
}
// one K-half stage step: 2 async16 (row srow and srow + rows/2)
__device__ __forceinline__ void stage2(const short* g, char* d, long rs, int off2) {
    async16(g, d);
    async16(g + rs, d + off2);
}

// ---------------------------------------------------------------------------
// Swizzle (T2, verified round 2: conflicts 4.19M -> 1.05M):
//   read col-block  qa = (q ^ ((r>>1)&3)) * 8 shorts   (32-short rows)
//   stage col-block sc = ((tid&3) ^ ((tid>>3)&3)) * 8 shorts
// 64-short rows (gemm_ln_k A): qa = ((ks*4+q) ^ (r&7))*8, src (t&7)^((t>>3)&7)
// ---------------------------------------------------------------------------

// ---------------------------------------------------------------------------
// 256x256 8-wave 4-phase/K-tile MFMA GEMM (T3+T4+T5, counted vmcnt).
// Pinned per-phase: barrier -> lgkmcnt(0) -> sched_barrier(0) -> setprio/MFMA.
// ---------------------------------------------------------------------------
#define MFMA_ROW(ai, accr)                                                    \
    accr[0] = __builtin_amdgcn_mfma_f32_16x16x32_bf16(ai, b[0], accr[0], 0, 0, 0); \
    accr[1] = __builtin_amdgcn_mfma_f32_16x16x32_bf16(ai, b[1], accr[1], 0, 0, 0); \
    accr[2] = __builtin_amdgcn_mfma_f32_16x16x32_bf16(ai, b[2], accr[2], 0, 0, 0); \
    accr[3] = __builtin_amdgcn_mfma_f32_16x16x32_bf16(ai, b[3], accr[3], 0, 0, 0);

#define MFMA_PHASE(B0)                                                        \
    __builtin_amdgcn_s_barrier();                                             \
    asm volatile("s_waitcnt lgkmcnt(0)" ::: "memory");                        \
    __builtin_amdgcn_sched_barrier(0);                                        \
    __builtin_amdgcn_s_setprio(1);                                            \
    MFMA_ROW(a[0], acc[B0 + 0])                                               \
    MFMA_ROW(a[1], acc[B0 + 1])                                               \
    MFMA_ROW(a[2], acc[B0 + 2])                                               \
    MFMA_ROW(a[3], acc[B0 + 3])                                               \
    __builtin_amdgcn_s_setprio(0);

template<int DO_GELU, int OUT_BF16, int ADD_RES>
__global__ __launch_bounds__(512, 2)
void gemm_mfma256_k(const __hip_bfloat16* __restrict__ A,
                    const __hip_bfloat16* __restrict__ WT,
                    const float* __restrict__ bias,
                    const float* __restrict__ R,
                    void* __restrict__ C,
                    int N, int K) {
    __shared__ __align__(16) char smem[131072];

    const int tid  = threadIdx.x;
    const int lane = tid & 63;
    const int wave = tid >> 6;

    // XCD-aware remap (bijective: nwg multiple of 8)
    const int Lid = blockIdx.y * gridDim.x + blockIdx.x;
    const int xcd = Lid & 7;
    const int idx = Lid >> 3;
    const int gx  = gridDim.x, gy8 = gridDim.y >> 3;
    const int m0 = (xcd * gy8 + idx / gx) * 256;
    const int n0 = (idx % gx) * 256;

    const int wm = (wave >> 2) * 128;     // 2 waves in M
    const int wn = (wave & 3) * 64;       // 4 waves in N
    const int r = lane & 15, q = lane >> 4;
    const int qa = (q ^ ((r >> 1) & 3)) * 8;   // T2-fixed de-swizzle

    // staging: thread t covers rows (t>>2) and (t>>2)+128, swizzled col-block
    const int srow = tid >> 2;
    const int sc = ((tid & 3) ^ ((tid >> 3) & 3)) * 8;
    const short* Ag = (const short*)A + (long)(m0 + srow) * K + sc;
    const short* Bg = (const short*)WT + (long)(n0 + srow) * K + sc;
    const long rs = (long)128 * K;        // +128 rows (shorts)

    floatx4 acc[8][4];
    #pragma unroll
    for (int i = 0; i < 8; i++)
        #pragma unroll
        for (int j = 0; j < 4; j++) acc[i][j] = (floatx4)0.f;

    const int NT = K >> 6;

    // prologue: tile 0 -> buf0, issue order [A-ks0, B-ks0, A-ks1, B-ks1]
    stage2(Ag,      smem         + tid * 16, rs, 8192);
    stage2(Bg,      smem + 32768 + tid * 16, rs, 8192);
    stage2(Ag + 32, smem + 16384 + tid * 16, rs, 8192);
    stage2(Bg + 32, smem + 49152 + tid * 16, rs, 8192);
    asm volatile("s_waitcnt vmcnt(4)" ::: "memory");  // A-ks0,B-ks0 landed
    __builtin_amdgcn_s_barrier();

    short8 a[4], b[4];
    for (int t = 0; t < NT; ++t) {
        const int cur = t & 1, nxt = cur ^ 1;
        const bool hn = (t + 1 < NT);
        const short* As = (const short*)(smem + cur * 65536);
        const short* Bs = (const short*)(smem + cur * 65536 + 32768);
        const short* Agt = Ag + (t + 1) * 64;
        const short* Bgt = Bg + (t + 1) * 64;
        char* Ad = smem + nxt * 65536;
        char* Bd = smem + nxt * 65536 + 32768;

        // ---- phase 1: ks=0, m-frags 0-3, all 4 B-frags ----
        #pragma unroll
        for (int i = 0; i < 4; i++)
            a[i] = *(const short8*)&As[(wm + i * 16 + r) * 32 + qa];
        #pragma unroll
        for (int j = 0; j < 4; j++)
            b[j] = *(const short8*)&Bs[(wn + j * 16 + r) * 32 + qa];
        if (hn) stage2(Agt, Ad + tid * 16, rs, 8192);          // A-ks0(t+1)
        MFMA_PHASE(0)
        __builtin_amdgcn_s_barrier();

        // ---- phase 2: ks=0, m-frags 4-7 (reuse b) ----
        #pragma unroll
        for (int i = 0; i < 4; i++)
            a[i] = *(const short8*)&As[(wm + 64 + i * 16 + r) * 32 + qa];
        if (hn) stage2(Bgt, Bd + tid * 16, rs, 8192);          // B-ks0(t+1)
        MFMA_PHASE(4)
        if (hn) asm volatile("s_waitcnt vmcnt(4)" ::: "memory"); // A/B-ks1(t) in
        else    asm volatile("s_waitcnt vmcnt(0)" ::: "memory"); // tail drain
        __builtin_amdgcn_s_barrier();

        // ---- phase 3: ks=1, m-frags 0-3, new B-frags ----
        #pragma unroll
        for (int i = 0; i < 4; i++)
            a[i] = *(const short8*)&As[8192 + (wm + i * 16 + r) * 32 + qa];
        #pragma unroll
        for (int j = 0; j < 4; j++)
            b[j] = *(const short8*)&Bs[8192 + (wn + j * 16 + r) * 32 + qa];
        if (hn) stage2(Agt + 32, Ad + 16384 + tid * 16, rs, 8192); // A-ks1(t+1)
        MFMA_PHASE(0)
        __builtin_amdgcn_s_barrier();

        // ---- phase 4: ks=1, m-frags 4-7 ----
        #pragma unroll
        for (int i = 0; i < 4; i++)
            a[i] = *(const short8*)&As[8192 + (wm + 64 + i * 16 + r) * 32 + qa];
        if (hn) stage2(Bgt + 32, Bd + 16384 + tid * 16, rs, 8192); // B-ks1(t+1)
        MFMA_PHASE(4)
        if (hn) asm volatile("s_waitcnt vmcnt(4)" ::: "memory"); // A/B-ks0(t+1) in
        __builtin_amdgcn_s_barrier();
    }

    // ---- epilogue: 4 chunks of 64 rows restaged through LDS, coalesced ----
    float* Ef = (float*)smem;
    const int erow = tid >> 3;       // 0..63
    const int ej = tid & 7;          // 0..7
    #pragma unroll
    for (int ch = 0; ch < 4; ch++) {
        __builtin_amdgcn_s_barrier();
        if ((wave >> 2) == (ch >> 1)) {
            #pragma unroll
            for (int mf2 = 0; mf2 < 4; mf2++) {
                const int mf = (ch & 1) * 4 + mf2;
                #pragma unroll
                for (int nf = 0; nf < 4; nf++)
                    #pragma unroll
                    for (int rg = 0; rg < 4; rg++)
                        Ef[(mf2 * 16 + q * 4 + rg) * 260 + wn + nf * 16 + r] =
                            acc[mf][nf][rg];
            }
        }
        __builtin_amdgcn_s_barrier();
        #pragma unroll
        for (int e = 0; e < 8; e++) {
            const int c4 = ej + e * 8;   // float4 column 0..63
            const long grow = (long)(m0 + ch * 64 + erow) * N + n0 + c4 * 4;
            const float4 v = *(const float4*)&Ef[erow * 260 + c4 * 4];
            const float4 bv = *(const float4*)&bias[n0 + c4 * 4];
            float o0 = v.x + bv.x, o1 = v.y + bv.y;
            float o2 = v.z + bv.z, o3 = v.w + bv.w;
            if (DO_GELU) {
                o0 = gelu_f(o0); o1 = gelu_f(o1);
                o2 = gelu_f(o2); o3 = gelu_f(o3);
            }
            if (ADD_RES) {
                const float4 rv = *(const float4*)&R[grow];
                o0 += rv.x; o1 += rv.y; o2 += rv.z; o3 += rv.w;
            }
            if (OUT_BF16) {
                ushort4 pk;
                pk.x = f2bf(o0); pk.y = f2bf(o1);
                pk.z = f2bf(o2); pk.w = f2bf(o3);
                *(ushort4*)((unsigned short*)C + grow) = pk;
            } else {
                *(float4*)((float*)C + grow) = make_float4(o0, o1, o2, o3);
            }
        }
    }
}

// ---------------------------------------------------------------------------
// bf16 MFMA GEMM 128x128, counted-vmcnt 2-body ledger (round-2 verified).
// ---------------------------------------------------------------------------
template<int DO_GELU, int OUT_BF16, int ADD_RES>
__global__ __launch_bounds__(256, 2)
void gemm_mfma_k(const __hip_bfloat16* __restrict__ A,
                 const __hip_bfloat16* __restrict__ WT,
                 const float* __restrict__ bias,
                 const float* __restrict__ R,
                 void* __restrict__ C,
                 int N, int K) {
    __shared__ __align__(16) char smem[65536];
    float* Ep = (float*)smem;

    const int tid  = threadIdx.x;
    const int lane = tid & 63;
    const int wave = tid >> 6;

    const int Lid = blockIdx.y * gridDim.x + blockIdx.x;
    const int xcd = Lid & 7;
    const int idx = Lid >> 3;
    const int gx  = gridDim.x, gy8 = gridDim.y >> 3;
    const int m0 = (xcd * gy8 + idx / gx) * 128;
    const int n0 = (idx % gx) * 128;

    const int wm = (wave >> 1) * 64, wn = (wave & 1) * 64;
    const int r = lane & 15, q = lane >> 4;
    const int qa = (q ^ ((r >> 1) & 3)) * 8;   // T2-fixed de-swizzle

    const int srow = tid >> 2;                 // 0..63
    const int sc = ((tid & 3) ^ ((tid >> 3) & 3)) * 8;
    const short* Ag = (const short*)A + (long)(m0 + srow) * K + sc;
    const short* Bg = (const short*)WT + (long)(n0 + srow) * K + sc;
    const long rs = (long)64 * K;              // +64 rows (shorts)

    floatx4 acc[4][4];
    #pragma unroll
    for (int i = 0; i < 4; i++)
        #pragma unroll
        for (int j = 0; j < 4; j++) acc[i][j] = (floatx4)0.f;

    const int NT = K >> 6;

    stage2(Ag,      smem + 0     + tid * 16, rs, 4096);
    stage2(Bg,      smem + 16384 + tid * 16, rs, 4096);
    stage2(Ag + 32, smem + 8192  + tid * 16, rs, 4096);
    stage2(Bg + 32, smem + 24576 + tid * 16, rs, 4096);
    asm volatile("s_waitcnt vmcnt(4)" ::: "memory");  // ks0 landed
    __builtin_amdgcn_s_barrier();
    __builtin_amdgcn_sched_barrier(0);

    short8 a[4], b[4];
    for (int t = 0; t < NT; ++t) {
        const int cur = t & 1, nxt = cur ^ 1;
        const bool hn = (t + 1 < NT);
        const short* As = (const short*)(smem + cur * 32768);
        const short* Bs = (const short*)(smem + cur * 32768 + 16384);
        const short* Agt = Ag + (t + 1) * 64;
        const short* Bgt = Bg + (t + 1) * 64;
        char* Ad = smem + nxt * 32768;
        char* Bd = smem + nxt * 32768 + 16384;

        // ---- body A: ks0 ----
        if (hn) {
            stage2(Agt, Ad + tid * 16, rs, 4096);
            stage2(Bgt, Bd + tid * 16, rs, 4096);
        }
        #pragma unroll
        for (int i = 0; i < 4; i++)
            a[i] = *(const short8*)&As[(wm + i * 16 + r) * 32 + qa];
        #pragma unroll
        for (int j = 0; j < 4; j++)
            b[j] = *(const short8*)&Bs[(wn + j * 16 + r) * 32 + qa];
        #pragma unroll
        for (int i = 0; i < 4; i++)
            #pragma unroll
            for (int j = 0; j < 4; j++)
                acc[i][j] = __builtin_amdgcn_mfma_f32_16x16x32_bf16(
                    a[i], b[j], acc[i][j], 0, 0, 0);
        __builtin_amdgcn_sched_barrier(0);
        if (hn) asm volatile("s_waitcnt vmcnt(4)" ::: "memory");
        else    asm volatile("s_waitcnt vmcnt(0)" ::: "memory");
        __builtin_amdgcn_s_barrier();
        __builtin_amdgcn_sched_barrier(0);

        // ---- body B: ks1 ----
        if (hn) {
            stage2(Agt + 32, Ad + 8192 + tid * 16, rs, 4096);
            stage2(Bgt + 32, Bd + 8192 + tid * 16, rs, 4096);
        }
        #pragma unroll
        for (int i = 0; i < 4; i++)
            a[i] = *(const short8*)&As[4096 + (wm + i * 16 + r) * 32 + qa];
        #pragma unroll
        for (int j = 0; j < 4; j++)
            b[j] = *(const short8*)&Bs[4096 + (wn + j * 16 + r) * 32 + qa];
        #pragma unroll
        for (int i = 0; i < 4; i++)
            #pragma unroll
            for (int j = 0; j < 4; j++)
                acc[i][j] = __builtin_amdgcn_mfma_f32_16x16x32_bf16(
                    a[i], b[j], acc[i][j], 0, 0, 0);
        __builtin_amdgcn_sched_barrier(0);
        if (hn) asm volatile("s_waitcnt vmcnt(4)" ::: "memory");
        __builtin_amdgcn_s_barrier();
        __builtin_amdgcn_sched_barrier(0);
    }

    // ---- epilogue: restage through LDS, coalesced postprocess + store ----
    const int erow = tid >> 5;          // 0..7
    const int ecol = (tid & 31) * 4;    // 0..124, float4 granularity
    const float4 bvec = *(const float4*)&bias[n0 + ecol];

    #pragma unroll
    for (int pass = 0; pass < 2; pass++) {
        if (pass) __syncthreads();
        if ((wave >> 1) == pass) {
            #pragma unroll
            for (int i = 0; i < 4; i++)
                #pragma unroll
                for (int j = 0; j < 4; j++)
                    #pragma unroll
                    for (int rg = 0; rg < 4; rg++)
                        Ep[(i * 16 + q * 4 + rg) * 132 + wn + j * 16 + r] =
                            acc[i][j][rg];
        }
        __syncthreads();
        #pragma unroll
        for (int it = 0; it < 8; it++) {
            const int row = it * 8 + erow;
            const long grow = (long)(m0 + pass * 64 + row) * N + n0 + ecol;
            const float4 v = *(const float4*)&Ep[row * 132 + ecol];
            float o0 = v.x + bvec.x, o1 = v.y + bvec.y;
            float o2 = v.z + bvec.z, o3 = v.w + bvec.w;
            if (DO_GELU) {
                o0 = gelu_f(o0); o1 = gelu_f(o1);
                o2 = gelu_f(o2); o3 = gelu_f(o3);
            }
            if (ADD_RES) {
                const float4 rv = *(const float4*)&R[grow];
                o0 += rv.x; o1 += rv.y; o2 += rv.z; o3 += rv.w;
            }
            if (OUT_BF16) {
                ushort4 pk;
                pk.x = f2bf(o0); pk.y = f2bf(o1);
                pk.z = f2bf(o2); pk.w = f2bf(o3);
                *(ushort4*)((unsigned short*)C + grow) = pk;
            } else {
                *(float4*)((float*)C + grow) = make_float4(o0, o1, o2, o3);
            }
        }
    }
}

// ---------------------------------------------------------------------------
// Fused GEMM(+bias+residual)+LayerNorm for N=512 shapes.
// Hout/Hb = LN(A@WT + bias + R)*g+be.  M mult 64, K mult 64. Replaces the
// GEMM->bufB->ln_k round-trip (saves 67MB HBM + a launch per call).
// BM=64 x BN=512 (full row in one block), BK=64, 512 thr: 8 waves 2Mx4N,
// wave-tile 32x128, acc[2][8]. LDS 144KB: 2 x (A[64][64sh] 8K + B0/B1
// [512][32sh] 32K each). Counted-vmcnt 2-body ledger, uniform 9 loads/
// thread/tile (bodyA: A-full 1 + B-ks0 4; bodyB: B-ks1 4):
//   prologue issue 9, vmcnt(4) [retires A0+B0ks0, leaves B0ks1=4]
//   bodyA: issue A(t+1)+Bks0(t+1)=5 -> read ks0 -> 16 MFMA -> vmcnt(4)
//          [retires Bks1(t)+A(t+1), leaves Bks0(t+1)=4] -> barrier
//   bodyB: issue Bks1(t+1)=4 -> read ks1 -> 16 MFMA -> vmcnt(4)
//          [retires Bks0(t+1), leaves Bks1(t+1)=4] -> barrier
// In-place R==Hout is safe: each block reads R only for its own 64 rows
// (epilogue) strictly before writing them; no cross-block row sharing.
// ---------------------------------------------------------------------------
__global__ __launch_bounds__(512, 1)
void gemm_ln_k(const __hip_bfloat16* __restrict__ A,
               const __hip_bfloat16* __restrict__ WT,
               const float* __restrict__ bias,
               const float* R,                    // no restrict: aliases Hout
               const float* __restrict__ g,
               const float* __restrict__ be,
               float* Hout,                       // no restrict: aliases R
               __hip_bfloat16* __restrict__ Hb,
               int K) {
    __shared__ __align__(16) char smem[147456];
    const int tid  = threadIdx.x;
    const int lane = tid & 63;
    const int wave = tid >> 6;

    // XCD swizzle (grid = 256 = 32 per XCD, bijective)
    const int Lid = blockIdx.x;
    const int m0 = ((Lid & 7) * 32 + (Lid >> 3)) * 64;

    const int wm2 = wave >> 2;            // 0/1 -> rows wm2*32
    const int wn4 = wave & 3;             // cols wn4*128
    const int r = lane & 15, q = lane >> 4;
    const int qaB  = (q ^ ((r >> 1) & 3)) * 8;   // B de-swizzle (32-short rows)
    const int qaA0 = ((q)     ^ (r & 7)) * 8;    // A ks0 (64-short rows)
    const int qaA1 = ((4 + q) ^ (r & 7)) * 8;    // A ks1

    // staging addresses (pre-swizzled sources, linear LDS dests)
    const int arow = tid >> 3;
    const int asb  = ((tid & 7) ^ ((tid >> 3) & 7)) * 8;
    const short* Ag = (const short*)A + (long)(m0 + arow) * K + asb;
    const int brow = tid >> 2;
    const int bsb  = ((tid & 3) ^ ((tid >> 3) & 3)) * 8;
    const short* Bg = (const short*)WT + (long)brow * K + bsb;
    const long brs = (long)128 * K;

    floatx4 acc[2][8];
    #pragma unroll
    for (int i = 0; i < 2; i++)
        #pragma unroll
        for (int j = 0; j < 8; j++) acc[i][j] = (floatx4)0.f;

    const int NTT = K >> 6;

    // prologue: tile 0 (A, Bks0, Bks1 = 9 loads/thread)
    {
        char* base = smem;
        async16(Ag, base + tid * 16);
        const short* p0 = Bg;
        char* d0 = base + 8192 + tid * 16;
        async16(p0, d0); async16(p0 + brs, d0 + 8192);
        async16(p0 + 2 * brs, d0 + 16384); async16(p0 + 3 * brs, d0 + 24576);
        const short* p1 = Bg + 32;
        char* d1 = base + 40960 + tid * 16;
        async16(p1, d1); async16(p1 + brs, d1 + 8192);
        async16(p1 + 2 * brs, d1 + 16384); async16(p1 + 3 * brs, d1 + 24576);
    }
    asm volatile("s_waitcnt vmcnt(4)" ::: "memory");  // A0 + B0ks0 landed
    __builtin_amdgcn_s_barrier();
    __builtin_amdgcn_sched_barrier(0);

    for (int t = 0; t < NTT; ++t) {
        const int cur = t & 1, nxt = cur ^ 1;
        const bool hn = (t + 1 < NTT);
        const short* As  = (const short*)(smem + cur * 73728);
        const short* B0s = (const short*)(smem + cur * 73728 + 8192);
        const short* B1s = (const short*)(smem + cur * 73728 + 40960);
        char* nb = smem + nxt * 73728;
        const long k1 = (long)(t + 1) * 64;

        // ---- body A: ks0 ----
        if (hn) {
            async16(Ag + k1, nb + tid * 16);                 // A(t+1): 1
            const short* p0 = Bg + k1;                       // Bks0(t+1): 4
            char* d0 = nb + 8192 + tid * 16;
            async16(p0, d0); async16(p0 + brs, d0 + 8192);
            async16(p0 + 2 * brs, d0 + 16384); async16(p0 + 3 * brs, d0 + 24576);
        }
        {
            short8 a0 = *(const short8*)&As[(wm2 * 32 +      r) * 64 + qaA0];
            short8 a1 = *(const short8*)&As[(wm2 * 32 + 16 + r) * 64 + qaA0];
            short8 b[8];
            #pragma unroll
            for (int nf = 0; nf < 8; nf++)
                b[nf] = *(const short8*)&B0s[(wn4 * 128 + nf * 16 + r) * 32 + qaB];
            #pragma unroll
            for (int nf = 0; nf < 8; nf++) {
                acc[0][nf] = __builtin_amdgcn_mfma_f32_16x16x32_bf16(a0, b[nf], acc[0][nf], 0, 0, 0);
                acc[1][nf] = __builtin_amdgcn_mfma_f32_16x16x32_bf16(a1, b[nf], acc[1][nf], 0, 0, 0);
            }
        }
        __builtin_amdgcn_sched_barrier(0);
        if (hn) asm volatile("s_waitcnt vmcnt(4)" ::: "memory"); // Bks1(t)+A(t+1) in
        else    asm volatile("s_waitcnt vmcnt(0)" ::: "memory");
        __builtin_amdgcn_s_barrier();
        __builtin_amdgcn_sched_barrier(0);

        // ---- body B: ks1 ----
        if (hn) {
            const short* p1 = Bg + k1 + 32;                  // Bks1(t+1): 4
            char* d1 = nb + 40960 + tid * 16;
            async16(p1, d1); async16(p1 + brs, d1 + 8192);
            async16(p1 + 2 * brs, d1 + 16384); async16(p1 + 3 * brs, d1 + 24576);
        }
        {
            short8 a0 = *(const short8*)&As[(wm2 * 32 +      r) * 64 + qaA1];
            short8 a1 = *(const short8*)&As[(wm2 * 32 + 16 + r) * 64 + qaA1];
            short8 b[8];
            #pragma unroll
            for (int nf = 0; nf < 8; nf++)
                b[nf] = *(const short8*)&B1s[(wn4 * 128 + nf * 16 + r) * 32 + qaB];
            #pragma unroll
            for (int nf = 0; nf < 8; nf++) {
                acc[0][nf] = __builtin_amdgcn_mfma_f32_16x16x32_bf16(a0, b[nf], acc[0][nf], 0, 0, 0);
                acc[1][nf] = __builtin_amdgcn_mfma_f32_16x16x32_bf16(a1, b[nf], acc[1][nf], 0, 0, 0);
            }
        }
        __builtin_amdgcn_sched_barrier(0);
        if (hn) asm volatile("s_waitcnt vmcnt(4)" ::: "memory"); // Bks0(t+1) in
        __builtin_amdgcn_s_barrier();
        __builtin_amdgcn_sched_barrier(0);
    }

    // ---- fused epilogue: restage -> +bias+R -> row LN stats -> store ----
    // Ef[32][522] fp32 (66816B, stride 522: writer rows q*4+rg spaced 4*522
    // words = 8 banks apart -> conflict-free); stat[32][2] after it.
    float* Ef = (float*)smem;
    float* stat = (float*)(smem + 66816);
    const float gl = g[tid], bl = be[tid], bv = bias[tid];

    #pragma unroll
    for (int ch = 0; ch < 2; ch++) {
        if (ch) __syncthreads();          // ch0 readers done before Ef reuse
        if (wm2 == ch) {
            #pragma unroll
            for (int mf = 0; mf < 2; mf++)
                #pragma unroll
                for (int nf = 0; nf < 8; nf++)
                    #pragma unroll
                    for (int rg = 0; rg < 4; rg++)
                        Ef[(mf * 16 + q * 4 + rg) * 522 + wn4 * 128 + nf * 16 + r] =
                            acc[mf][nf][rg];
        }
        __syncthreads();
        const int gm = m0 + ch * 32;
        // bias + residual, coalesced (thread t owns column t of 32 rows)
        #pragma unroll 8
        for (int k = 0; k < 32; k++)
            Ef[k * 522 + tid] += bv + R[(long)(gm + k) * 512 + tid];
        __syncthreads();
        // per-row stats: 16 threads per row, 32 cols each
        {
            const int row = tid >> 4, cc = tid & 15;
            float s = 0.f, ss = 0.f;
            #pragma unroll 8
            for (int j = 0; j < 32; j++) {
                const float v = Ef[row * 522 + cc + 16 * j];
                s += v; ss += v * v;
            }
            #pragma unroll
            for (int off = 1; off < 16; off <<= 1) {
                s  += __shfl_xor(s, off);
                ss += __shfl_xor(ss, off);
            }
            const float mu  = s * (1.0f / 512.0f);
            const float var = fmaxf(ss * (1.0f / 512.0f) - mu * mu, 0.f);
            const float inv = 1.0f / sqrtf(var + 1e-5f);
            if (cc == 0) { stat[row * 2] = mu; stat[row * 2 + 1] = inv; }
        }
        __syncthreads();
        // normalize + store, coalesced
        #pragma unroll 8
        for (int k = 0; k < 32; k++) {
            const float v  = Ef[k * 522 + tid];
            const float o  = (v - stat[k * 2]) * stat[k * 2 + 1] * gl + bl;
            const long idx = (long)(gm + k) * 512 + tid;
            Hout[idx] = o;
            ((unsigned short*)Hb)[idx] = f2bf(o);
        }
    }
}

// ---------------------------------------------------------------------------
// WT[l][n][k] = (bf16) W[l][k][n]
// ---------------------------------------------------------------------------
__global__ __launch_bounds__(256)
void transpose_cast_k(const float* __restrict__ W, __hip_bfloat16* __restrict__ WT,
                      int K, int N) {
    __shared__ float tile[32][33];
    const float* Wl = W + (long)blockIdx.z * K * N;
    __hip_bfloat16* WTl = WT + (long)blockIdx.z * K * N;
    const int n0 = blockIdx.x * 32, k0 = blockIdx.y * 32;
    const int tx = threadIdx.x & 31, ty = threadIdx.x >> 5;
    for (int rr = ty; rr < 32; rr += 8)
        tile[rr][tx] = Wl[(long)(k0 + rr) * N + n0 + tx];
    __syncthreads();
    for (int rr = ty; rr < 32; rr += 8)
        WTl[(long)(n0 + rr) * K + k0 + tx] = __float2bfloat16(tile[tx][rr]);
}

// ---------------------------------------------------------------------------
// fp32 tiled GEMM (in-proj only: M=16384, N=512, K=32)
// ---------------------------------------------------------------------------
template<int DO_GELU>
__global__ __launch_bounds__(256)
void gemm_bias_k(const float* __restrict__ A, long lda,
                 const float* __restrict__ W,
                 const float* __restrict__ bias,
                 float* __restrict__ C,
                 int M, int N, int K) {
    __shared__ float As[16][64];
    __shared__ float Ws[16][64];
    const int tx = threadIdx.x;
    const int ty = threadIdx.y;
    const int tid = ty * 16 + tx;
    const int m0 = blockIdx.y * 64;
    const int n0 = blockIdx.x * 64;
    float acc[4][4] = {};
    for (int k0 = 0; k0 < K; k0 += 16) {
        #pragma unroll
        for (int e = tid; e < 64 * 16; e += 256) {
            int m = e >> 4, k = e & 15;
            float v = 0.f;
            if (m0 + m < M) v = A[(long)(m0 + m) * lda + k0 + k];
            As[k][m] = v;
        }
        #pragma unroll
        for (int e = tid; e < 16 * 64; e += 256) {
            int k = e >> 6, n = e & 63;
            float v = 0.f;
            if (n0 + n < N) v = W[(long)(k0 + k) * N + n0 + n];
            Ws[k][n] = v;
        }
        __syncthreads();
        #pragma unroll
        for (int kk = 0; kk < 16; kk++) {
            float a[4], w[4];
            #pragma unroll
            for (int i = 0; i < 4; i++) a[i] = As[kk][ty * 4 + i];
            #pragma unroll
            for (int j = 0; j < 4; j++) w[j] = Ws[kk][tx * 4 + j];
            #pragma unroll
            for (int i = 0; i < 4; i++)
                #pragma unroll
                for (int j = 0; j < 4; j++)
                    acc[i][j] += a[i] * w[j];
        }
        __syncthreads();
    }
    #pragma unroll
    for (int i = 0; i < 4; i++) {
        int m = m0 + ty * 4 + i;
        if (m >= M) continue;
        #pragma unroll
        for (int j = 0; j < 4; j++) {
            int n = n0 + tx * 4 + j;
            if (n >= N) continue;
            float v = acc[i][j] + bias[n];
            if (DO_GELU) v = gelu_f(v);
            C[(long)m * N + n] = v;
        }
    }
}

// ---------------------------------------------------------------------------
// Wave-per-row LN (retained, unused by the hot path)
// ---------------------------------------------------------------------------
__global__ __launch_bounds__(256)
void ln_k(const float* __restrict__ X,
          const float* __restrict__ g,
          const float* __restrict__ be,
          float* __restrict__ H,
          __hip_bfloat16* __restrict__ Hb) {
    const int row = blockIdx.x * 4 + (threadIdx.x >> 6);
    const int lane = threadIdx.x & 63;
    const float* xp = X + (long)row * D_ + lane * 8;
    const float4 a = *(const float4*)xp;
    const float4 c = *(const float4*)(xp + 4);
    float s = a.x + a.y + a.z + a.w + c.x + c.y + c.z + c.w;
    #pragma unroll
    for (int off = 1; off < 64; off <<= 1) s += __shfl_xor(s, off);
    const float mu = s * (1.0f / D_);
    float d[8] = { a.x - mu, a.y - mu, a.z - mu, a.w - mu,
                   c.x - mu, c.y - mu, c.z - mu, c.w - mu };
    float ss = 0.f;
    #pragma unroll
    for (int e = 0; e < 8; e++) ss += d[e] * d[e];
    #pragma unroll
    for (int off = 1; off < 64; off <<= 1) ss += __shfl_xor(ss, off);
    const float inv = 1.0f / sqrtf(ss * (1.0f / D_) + 1e-5f);
    const float4 g0 = *(const float4*)(g + lane * 8);
    const float4 g1 = *(const float4*)(g + lane * 8 + 4);
    const float4 e0 = *(const float4*)(be + lane * 8);
    const float4 e1 = *(const float4*)(be + lane * 8 + 4);
    const float gv[8] = { g0.x, g0.y, g0.z, g0.w, g1.x, g1.y, g1.z, g1.w };
    const float ev[8] = { e0.x, e0.y, e0.z, e0.w, e1.x, e1.y, e1.z, e1.w };
    float o[8];
    short8 pk;
    #pragma unroll
    for (int e = 0; e < 8; e++) {
        o[e] = d[e] * inv * gv[e] + ev[e];
        pk[e] = (short)f2bf(o[e]);
    }
    float* hp = H + (long)row * D_ + lane * 8;
    *(float4*)hp = make_float4(o[0], o[1], o[2], o[3]);
    *(float4*)(hp + 4) = make_float4(o[4], o[5], o[6], o[7]);
    *(short8*)((unsigned short*)Hb + (long)row * D_ + lane * 8) = pk;
}

// ---------------------------------------------------------------------------
// h = gelu(layernorm(X)) + pe ; also bf16 copy hb  (runs once)
// ---------------------------------------------------------------------------
__global__ __launch_bounds__(256)
void ln_gelu_pos_k(const float* __restrict__ X,
                   const float* __restrict__ g,
                   const float* __restrict__ be,
                   float* __restrict__ Hout,
                   __hip_bfloat16* __restrict__ Hb) {
    const int row = blockIdx.x;
    const int s = row & (S_ - 1);
    const int t = threadIdx.x;
    const float* x = X + (long)row * D_;
    float v0 = x[t], v1 = x[t + 256];
    __shared__ float red[256];
    red[t] = v0 + v1;
    __syncthreads();
    for (int off = 128; off; off >>= 1) {
        if (t < off) red[t] += red[t + off];
        __syncthreads();
    }
    float mu = red[0] * (1.0f / D_);
    __syncthreads();
    float d0 = v0 - mu, d1 = v1 - mu;
    red[t] = d0 * d0 + d1 * d1;
    __syncthreads();
    for (int off = 128; off; off >>= 1) {
        if (t < off) red[t] += red[t + off];
        __syncthreads();
    }
    float var = red[0] * (1.0f / D_);
    float inv = 1.0f / sqrtf(var + 1e-5f);
    float o0 = gelu_f(d0 * inv * g[t] + be[t]);
    float o1 = gelu_f(d1 * inv * g[t + 256] + be[t + 256]);
    {
        int d = t, i = d >> 1;
        float dv = expf((float)(2 * i) * (-9.210340371976184f / 512.0f));
        float ang = (float)s * dv;
        o0 += (d & 1) ? cosf(ang) : sinf(ang);
    }
    {
        int d = t + 256, i = d >> 1;
        float dv = expf((float)(2 * i) * (-9.210340371976184f / 512.0f));
        float ang = (float)s * dv;
        o1 += (d & 1) ? cosf(ang) : sinf(ang);
    }
    Hout[(long)row * D_ + t] = o0;
    Hout[(long)row * D_ + t + 256] = o1;
    Hb[(long)row * D_ + t] = __float2bfloat16(o0);
    Hb[(long)row * D_ + t + 256] = __float2bfloat16(o1);
}

// ---------------------------------------------------------------------------
// MFMA flash attention (verified structure, unchanged)
// ---------------------------------------------------------------------------
#define LDT 72
__global__ __launch_bounds__(256)
void attn_mfma_k(const __hip_bfloat16* __restrict__ qkv,
                 __hip_bfloat16* __restrict__ O) {
    const int qt = blockIdx.x;
    const int bh = blockIdx.y;
    const int b = bh >> 3, h = bh & (H_ - 1);
    const int tid = threadIdx.x;
    const int wave = tid >> 6, lane = tid & 63;
    const int ln = lane & 15, quad = lane >> 4;
    const int wm = wave * 32;
    const int i0 = qt * 128;

    __shared__ unsigned short Qs[128 * LDT];
    __shared__ unsigned short Ks[64 * LDT];
    __shared__ unsigned short Vt[64 * LDT];
    __shared__ unsigned short Ps[128 * LDT];
    __shared__ float stat[128];

    const unsigned short* base = (const unsigned short*)qkv + (long)b * S_ * (3 * D_);

    {
        const int r0 = tid >> 3, c0 = (tid & 7) * 8;
        #pragma unroll
        for (int i = 0; i < 4; i++) {
            const int rw = i * 32 + r0;
            *(short8*)&Qs[rw * LDT + c0] =
                *(const short8*)(base + (long)(i0 + rw) * (3 * D_) + h * HD_ + c0);
        }
    }

    float m_i[2] = { -INFINITY, -INFINITY };
    float l_i[2] = { 0.f, 0.f };
    floatx4 o_acc[2][4];
    #pragma unroll
    for (int i = 0; i < 2; i++)
        #pragma unroll
        for (int j = 0; j < 4; j++) o_acc[i][j] = (floatx4)0.f;

    const int kr = tid >> 2, kc = (tid & 3) * 16;
    const int vj = tid & 63, vc = (tid >> 6) * 16;

    const int ktmax = 2 * qt + 1;
    for (int kt = 0; kt <= ktmax; kt++) {
        const int j0 = kt * 64;
        {
            const unsigned short* kp = base + (long)(j0 + kr) * (3 * D_) + D_ + h * HD_ + kc;
            *(short8*)&Ks[kr * LDT + kc]     = *(const short8*)(kp);
            *(short8*)&Ks[kr * LDT + kc + 8] = *(const short8*)(kp + 8);
            const unsigned short* vp = base + (long)(j0 + vj) * (3 * D_) + 2 * D_ + h * HD_ + vc;
            short8 v0 = *(const short8*)(vp);
            short8 v1 = *(const short8*)(vp + 8);
            #pragma unroll
            for (int e = 0; e < 8; e++) {
                Vt[(vc + e) * LDT + vj]     = (unsigned short)v0[e];
                Vt[(vc + 8 + e) * LDT + vj] = (unsigned short)v1[e];
            }
        }
        __syncthreads();

        floatx4 sa[4][2];
        #pragma unroll
        for (int mt = 0; mt < 4; mt++)
            #pragma unroll
            for (int nt = 0; nt < 2; nt++) sa[mt][nt] = (floatx4)0.f;
        #pragma unroll
        for (int c = 0; c < 2; c++) {
            short8 kf[4], qf[2];
            #pragma unroll
            for (int mt = 0; mt < 4; mt++)
                kf[mt] = *(const short8*)&Ks[(mt * 16 + ln) * LDT + c * 32 + quad * 8];
            #pragma unroll
            for (int nt = 0; nt < 2; nt++)
                qf[nt] = *(const short8*)&Qs[(wm + nt * 16 + ln) * LDT + c * 32 + quad * 8];
            #pragma unroll
            for (int mt = 0; mt < 4; mt++)
                #pragma unroll
                for (int nt = 0; nt < 2; nt++)
                    sa[mt][nt] = __builtin_amdgcn_mfma_f32_16x16x32_bf16(
                        kf[mt], qf[nt], sa[mt][nt], 0, 0, 0);
        }

        const bool domask = (kt >= 2 * qt);
        #pragma unroll
        for (int nt = 0; nt < 2; nt++) {
            const int qg = i0 + wm + nt * 16 + ln;
            float mx = -INFINITY;
            #pragma unroll
            for (int mt = 0; mt < 4; mt++)
                #pragma unroll
                for (int rg = 0; rg < 4; rg++) {
                    float v = sa[mt][nt][rg] * 0.125f;
                    if (domask && (j0 + mt * 16 + quad * 4 + rg > qg)) v = -INFINITY;
                    sa[mt][nt][rg] = v;
                    mx = fmaxf(mx, v);
                }
            mx = fmaxf(mx, __shfl_xor(mx, 16));
            mx = fmaxf(mx, __shfl_xor(mx, 32));
            const float mn = fmaxf(m_i[nt], mx);
            const float alpha = __expf(m_i[nt] - mn);
            m_i[nt] = mn;
            float ls = 0.f;
            #pragma unroll
            for (int mt = 0; mt < 4; mt++) {
                ushort4 pk;
                float p0 = __expf(sa[mt][nt][0] - mn);
                float p1 = __expf(sa[mt][nt][1] - mn);
                float p2 = __expf(sa[mt][nt][2] - mn);
                float p3 = __expf(sa[mt][nt][3] - mn);
                ls += p0 + p1 + p2 + p3;
                pk.x = f2bf(p0); pk.y = f2bf(p1); pk.z = f2bf(p2); pk.w = f2bf(p3);
                *(ushort4*)&Ps[(wm + nt * 16 + ln) * LDT + mt * 16 + quad * 4] = pk;
            }
            ls += __shfl_xor(ls, 16);
            ls += __shfl_xor(ls, 32);
            l_i[nt] = l_i[nt] * alpha + ls;
            if (quad == 0) stat[wm + nt * 16 + ln] = alpha;
        }

        #pragma unroll
        for (int mt2 = 0; mt2 < 2; mt2++) {
            #pragma unroll
            for (int rg = 0; rg < 4; rg++) {
                const float a = stat[wm + mt2 * 16 + quad * 4 + rg];
                #pragma unroll
                for (int nt = 0; nt < 4; nt++) o_acc[mt2][nt][rg] *= a;
            }
        }

        #pragma unroll
        for (int c = 0; c < 2; c++) {
            short8 pf[2], vf[4];
            #pragma unroll
            for (int mt2 = 0; mt2 < 2; mt2++)
                pf[mt2] = *(const short8*)&Ps[(wm + mt2 * 16 + ln) * LDT + c * 32 + quad * 8];
            #pragma unroll
            for (int nt = 0; nt < 4; nt++)
                vf[nt] = *(const short8*)&Vt[(nt * 16 + ln) * LDT + c * 32 + quad * 8];
            #pragma unroll
            for (int mt2 = 0; mt2 < 2; mt2++)
                #pragma unroll
                for (int nt = 0; nt < 4; nt++)
                    o_acc[mt2][nt] = __builtin_amdgcn_mfma_f32_16x16x32_bf16(
                        pf[mt2], vf[nt], o_acc[mt2][nt], 0, 0, 0);
        }
        __syncthreads();
    }

    if (quad == 0) {
        stat[wm + ln]      = l_i[0];
        stat[wm + 16 + ln] = l_i[1];
    }
    unsigned short* Og = (unsigned short*)O;
    #pragma unroll
    for (int mt2 = 0; mt2 < 2; mt2++) {
        #pragma unroll
        for (int rg = 0; rg < 4; rg++) {
            const float linv = 1.0f / stat[wm + mt2 * 16 + quad * 4 + rg];
            const long row = (long)(b * S_ + i0 + wm + mt2 * 16 + quad * 4 + rg);
            #pragma unroll
            for (int nt = 0; nt < 4; nt++)
                Og[row * D_ + h * HD_ + nt * 16 + ln] =
                    f2bf(o_acc[mt2][nt][rg] * linv);
        }
    }
}

// ---------------------------------------------------------------------------
// Head kernels
// ---------------------------------------------------------------------------
__global__ __launch_bounds__(256)
void head1_k(const float* __restrict__ h, const float* __restrict__ w1,
             const float* __restrict__ b1, float* __restrict__ th) {
    __shared__ float hs[D_];
    const int b = blockIdx.x, n = threadIdx.x;
    const float* hr = h + (long)(b * S_ + S_ - 1) * D_;
    hs[n] = hr[n];
    hs[n + 256] = hr[n + 256];
    __syncthreads();
    float s = 0.f;
    #pragma unroll 8
    for (int k = 0; k < D_; k++) s += hs[k] * w1[(long)k * 256 + n];
    th[b * 256 + n] = gelu_f(s + b1[n]);
}

__global__ __launch_bounds__(64)
void head2_k(const float* __restrict__ th, const float* __restrict__ w2,
             const float* __restrict__ b2, float* __restrict__ out) {
    const int b = blockIdx.x, lane = threadIdx.x;
    const float* t = th + b * 256;
    float s0 = 0.f, s1 = 0.f, s2 = 0.f;
    #pragma unroll
    for (int e = 0; e < 4; e++) {
        const int k = lane * 4 + e;
        const float tv = t[k];
        s0 += tv * w2[k * 3 + 0];
        s1 += tv * w2[k * 3 + 1];
        s2 += tv * w2[k * 3 + 2];
    }
    #pragma unroll
    for (int off = 1; off < 64; off <<= 1) {
        s0 += __shfl_xor(s0, off);
        s1 += __shfl_xor(s1, off);
        s2 += __shfl_xor(s2, off);
    }
    if (lane == 0) {
        out[b * 3 + 0] = s0 + b2[0];
        out[b * 3 + 1] = s1 + b2[1];
        out[b * 3 + 2] = s2 + b2[2];
    }
}

// ---------------------------------------------------------------------------
extern "C" void kernel_launch(void* const* d_in, const int* in_sizes, int n_in,
                              void* d_out, int out_size, void* d_ws, size_t ws_size,
                              hipStream_t stream) {
    const float* x     = (const float*)d_in[0];
    const float* w_in  = (const float*)d_in[1];
    const float* b_in  = (const float*)d_in[2];
    const float* g_in  = (const float*)d_in[3];
    const float* be_in = (const float*)d_in[4];
    const float* w_qkv = (const float*)d_in[5];
    const float* b_qkv = (const float*)d_in[6];
    const float* w_out = (const float*)d_in[7];
    const float* b_out = (const float*)d_in[8];
    const float* g1    = (const float*)d_in[9];
    const float* be1   = (const float*)d_in[10];
    const float* w_ff1 = (const float*)d_in[11];
    const float* b_ff1 = (const float*)d_in[12];
    const float* w_ff2 = (const float*)d_in[13];
    const float* b_ff2 = (const float*)d_in[14];
    const float* g2    = (const float*)d_in[15];
    const float* be2   = (const float*)d_in[16];
    const float* w_h1  = (const float*)d_in[17];
    const float* b_h1  = (const float*)d_in[18];
    const float* w_h2  = (const float*)d_in[19];
    const float* b_h2  = (const float*)d_in[20];
    float* out = (float*)d_out;

    float* h    = (float*)d_ws;
    float* bufB = h + (long)M_ * D_;
    float* th   = bufB + (long)M_ * D_;
    __hip_bfloat16* hb    = (__hip_bfloat16*)(th + 32 * 256);
    __hip_bfloat16* attb  = hb + (long)M_ * D_;
    __hip_bfloat16* bufAb = attb + (long)M_ * D_;
    __hip_bfloat16* qkvT  = bufAb + (long)M_ * FF_;
    __hip_bfloat16* outT  = qkvT + (long)L_ * (3 * D_) * D_;
    __hip_bfloat16* ff1T  = outT + (long)L_ * D_ * D_;
    __hip_bfloat16* ff2T  = ff1T + (long)L_ * FF_ * D_;

    dim3 blk(16, 16);

    transpose_cast_k<<<dim3((3 * D_) / 32, D_ / 32, L_), 256, 0, stream>>>(w_qkv, qkvT, D_, 3 * D_);
    transpose_cast_k<<<dim3(D_ / 32, D_ / 32, L_), 256, 0, stream>>>(w_out, outT, D_, D_);
    transpose_cast_k<<<dim3(FF_ / 32, D_ / 32, L_), 256, 0, stream>>>(w_ff1, ff1T, D_, FF_);
    transpose_cast_k<<<dim3(D_ / 32, FF_ / 32, L_), 256, 0, stream>>>(w_ff2, ff2T, FF_, D_);

    gemm_bias_k<0><<<dim3(D_ / 64, M_ / 64), blk, 0, stream>>>(
        x, IN_, w_in, b_in, bufB, M_, D_, IN_);
    ln_gelu_pos_k<<<M_, 256, 0, stream>>>(bufB, g_in, be_in, h, hb);

    for (int l = 0; l < L_; l++) {
        // qkv -> bf16 bufAb (128^2 counted-vmcnt)
        gemm_mfma_k<0, 1, 0><<<dim3((3 * D_) / 128, M_ / 128), 256, 0, stream>>>(
            hb, qkvT + (long)l * (3 * D_) * D_, b_qkv + l * 3 * D_, nullptr,
            bufAb, 3 * D_, D_);
        attn_mfma_k<<<dim3(S_ / 128, B_ * H_), 256, 0, stream>>>(bufAb, attb);
        // fused: h = LN(attb @ outT + b_out + h)  (writes h fp32 + hb bf16)
        gemm_ln_k<<<256, 512, 0, stream>>>(
            attb, outT + (long)l * D_ * D_, b_out + l * D_, h,
            g1 + l * D_, be1 + l * D_, h, hb, D_);
        // ff1 -> bf16 bufAb (gelu)  (256^2 4-phase pinned)
        gemm_mfma256_k<1, 1, 0><<<dim3(FF_ / 256, M_ / 256), 512, 0, stream>>>(
            hb, ff1T + (long)l * FF_ * D_, b_ff1 + l * FF_, nullptr,
            bufAb, FF_, D_);
        // fused: h = LN(bufAb @ ff2T + b_ff2 + h)
        gemm_ln_k<<<256, 512, 0, stream>>>(
            bufAb, ff2T + (long)l * D_ * FF_, b_ff2 + l * D_, h,
            g2 + l * D_, be2 + l * D_, h, hb, FF_);
    }

    head1_k<<<B_, 256, 0, stream>>>(h, w_h1, b_h1, th);
    head2_k<<<B_, 64, 0, stream>>>(th, w_h2, b_h2, out);
}

// Round 6
// 1592.229 us; speedup vs baseline: 1.0598x; 1.0288x over previous
//
#include <hip/hip_runtime.h>
#include <hip/hip_bf16.h>
#include <math.h>

#define D_   512
#define H_   8
#define HD_  64
#define L_   6
#define FF_  2048
#define IN_  32
#define OUT_ 3
#define S_   512
#define B_   32
#define M_   (B_ * S_)   // 16384 token rows

typedef __attribute__((ext_vector_type(8))) short short8;
typedef __attribute__((ext_vector_type(4))) float floatx4;

// Branchless gelu: 0.5x(1+erf(x/sqrt2)), erf via A&S 7.1.26 (max err 1.5e-7).
__device__ __forceinline__ float gelu_f(float x) {
    const float ax = fabsf(x) * 0.70710678118654752f;
    const float t = __builtin_amdgcn_rcpf(fmaf(0.3275911f, ax, 1.0f));
    float p = fmaf(1.061405429f, t, -1.453152027f);
    p = fmaf(p, t, 1.421413741f);
    p = fmaf(p, t, -0.284496736f);
    p = fmaf(p, t, 0.254829592f);
    p = p * t;
    const float e = __expf(-ax * ax);
    const float er = copysignf(fmaf(-p, e, 1.0f), x);
    return 0.5f * x * (1.0f + er);
}
__device__ __forceinline__ float bf2f(unsigned short u) {
    union { unsigned int i; float f; } c; c.i = ((unsigned)u) << 16; return c.f;
}
__device__ __forceinline__ unsigned short f2bf(float v) {
    __hip_bfloat16 t = __float2bfloat16(v);
    return *(unsigned short*)&t;
}
__device__ __forceinline__ void async16(const void* g, void* l) {
    __builtin_amdgcn_global_load_lds(
        (const __attribute__((address_space(1))) unsigned int*)g,
        (__attribute__((address_space(3))) unsigned int*)l, 16, 0, 0);
}
// one K-half stage step: 2 async16 (row srow and srow + rows/2)
__device__ __forceinline__ void stage2(const short* g, char* d, long rs, int off2) {
    async16(g, d);
    async16(g + rs, d + off2);
}

// ---------------------------------------------------------------------------
// Swizzle (T2, verified round 2: conflicts 4.19M -> 1.05M):
//   read col-block  qa = (q ^ ((r>>1)&3)) * 8 shorts   (32-short rows)
//   stage col-block sc = ((tid&3) ^ ((tid>>3)&3)) * 8 shorts
// 64-short rows (gemm_ln_k A): qa = ((ks*4+q) ^ (r&7))*8, src (t&7)^((t>>3)&7)
// ---------------------------------------------------------------------------

// ---------------------------------------------------------------------------
// bf16 MFMA GEMM 128x128, counted-vmcnt 2-body ledger (round-2 verified;
// 64KB LDS -> 2 blocks/CU so epilogue BW bursts overlap other blocks' loops).
// ROUND 6: ff1 routed here too (256^2 kernel removed — its 128KB LDS forced
// 1 block/CU, serializing the 65MB C-write burst against the K-loop;
// MfmaUtil 23% == exactly its compute floor, idle 77% was that drain).
// ---------------------------------------------------------------------------
template<int DO_GELU, int OUT_BF16, int ADD_RES>
__global__ __launch_bounds__(256, 2)
void gemm_mfma_k(const __hip_bfloat16* __restrict__ A,
                 const __hip_bfloat16* __restrict__ WT,
                 const float* __restrict__ bias,
                 const float* __restrict__ R,
                 void* __restrict__ C,
                 int N, int K) {
    __shared__ __align__(16) char smem[65536];
    float* Ep = (float*)smem;

    const int tid  = threadIdx.x;
    const int lane = tid & 63;
    const int wave = tid >> 6;

    const int Lid = blockIdx.y * gridDim.x + blockIdx.x;
    const int xcd = Lid & 7;
    const int idx = Lid >> 3;
    const int gx  = gridDim.x, gy8 = gridDim.y >> 3;
    const int m0 = (xcd * gy8 + idx / gx) * 128;
    const int n0 = (idx % gx) * 128;

    const int wm = (wave >> 1) * 64, wn = (wave & 1) * 64;
    const int r = lane & 15, q = lane >> 4;
    const int qa = (q ^ ((r >> 1) & 3)) * 8;   // T2-fixed de-swizzle

    const int srow = tid >> 2;                 // 0..63
    const int sc = ((tid & 3) ^ ((tid >> 3) & 3)) * 8;
    const short* Ag = (const short*)A + (long)(m0 + srow) * K + sc;
    const short* Bg = (const short*)WT + (long)(n0 + srow) * K + sc;
    const long rs = (long)64 * K;              // +64 rows (shorts)

    floatx4 acc[4][4];
    #pragma unroll
    for (int i = 0; i < 4; i++)
        #pragma unroll
        for (int j = 0; j < 4; j++) acc[i][j] = (floatx4)0.f;

    const int NT = K >> 6;

    stage2(Ag,      smem + 0     + tid * 16, rs, 4096);
    stage2(Bg,      smem + 16384 + tid * 16, rs, 4096);
    stage2(Ag + 32, smem + 8192  + tid * 16, rs, 4096);
    stage2(Bg + 32, smem + 24576 + tid * 16, rs, 4096);
    asm volatile("s_waitcnt vmcnt(4)" ::: "memory");  // ks0 landed
    __builtin_amdgcn_s_barrier();
    __builtin_amdgcn_sched_barrier(0);

    short8 a[4], b[4];
    for (int t = 0; t < NT; ++t) {
        const int cur = t & 1, nxt = cur ^ 1;
        const bool hn = (t + 1 < NT);
        const short* As = (const short*)(smem + cur * 32768);
        const short* Bs = (const short*)(smem + cur * 32768 + 16384);
        const short* Agt = Ag + (t + 1) * 64;
        const short* Bgt = Bg + (t + 1) * 64;
        char* Ad = smem + nxt * 32768;
        char* Bd = smem + nxt * 32768 + 16384;

        // ---- body A: ks0 ----
        if (hn) {
            stage2(Agt, Ad + tid * 16, rs, 4096);
            stage2(Bgt, Bd + tid * 16, rs, 4096);
        }
        #pragma unroll
        for (int i = 0; i < 4; i++)
            a[i] = *(const short8*)&As[(wm + i * 16 + r) * 32 + qa];
        #pragma unroll
        for (int j = 0; j < 4; j++)
            b[j] = *(const short8*)&Bs[(wn + j * 16 + r) * 32 + qa];
        #pragma unroll
        for (int i = 0; i < 4; i++)
            #pragma unroll
            for (int j = 0; j < 4; j++)
                acc[i][j] = __builtin_amdgcn_mfma_f32_16x16x32_bf16(
                    a[i], b[j], acc[i][j], 0, 0, 0);
        __builtin_amdgcn_sched_barrier(0);
        if (hn) asm volatile("s_waitcnt vmcnt(4)" ::: "memory");
        else    asm volatile("s_waitcnt vmcnt(0)" ::: "memory");
        __builtin_amdgcn_s_barrier();
        __builtin_amdgcn_sched_barrier(0);

        // ---- body B: ks1 ----
        if (hn) {
            stage2(Agt + 32, Ad + 8192 + tid * 16, rs, 4096);
            stage2(Bgt + 32, Bd + 8192 + tid * 16, rs, 4096);
        }
        #pragma unroll
        for (int i = 0; i < 4; i++)
            a[i] = *(const short8*)&As[4096 + (wm + i * 16 + r) * 32 + qa];
        #pragma unroll
        for (int j = 0; j < 4; j++)
            b[j] = *(const short8*)&Bs[4096 + (wn + j * 16 + r) * 32 + qa];
        #pragma unroll
        for (int i = 0; i < 4; i++)
            #pragma unroll
            for (int j = 0; j < 4; j++)
                acc[i][j] = __builtin_amdgcn_mfma_f32_16x16x32_bf16(
                    a[i], b[j], acc[i][j], 0, 0, 0);
        __builtin_amdgcn_sched_barrier(0);
        if (hn) asm volatile("s_waitcnt vmcnt(4)" ::: "memory");
        __builtin_amdgcn_s_barrier();
        __builtin_amdgcn_sched_barrier(0);
    }

    // ---- epilogue: restage through LDS, coalesced postprocess + store ----
    const int erow = tid >> 5;          // 0..7
    const int ecol = (tid & 31) * 4;    // 0..124, float4 granularity
    const float4 bvec = *(const float4*)&bias[n0 + ecol];

    #pragma unroll
    for (int pass = 0; pass < 2; pass++) {
        if (pass) __syncthreads();
        if ((wave >> 1) == pass) {
            #pragma unroll
            for (int i = 0; i < 4; i++)
                #pragma unroll
                for (int j = 0; j < 4; j++)
                    #pragma unroll
                    for (int rg = 0; rg < 4; rg++)
                        Ep[(i * 16 + q * 4 + rg) * 132 + wn + j * 16 + r] =
                            acc[i][j][rg];
        }
        __syncthreads();
        #pragma unroll
        for (int it = 0; it < 8; it++) {
            const int row = it * 8 + erow;
            const long grow = (long)(m0 + pass * 64 + row) * N + n0 + ecol;
            const float4 v = *(const float4*)&Ep[row * 132 + ecol];
            float o0 = v.x + bvec.x, o1 = v.y + bvec.y;
            float o2 = v.z + bvec.z, o3 = v.w + bvec.w;
            if (DO_GELU) {
                o0 = gelu_f(o0); o1 = gelu_f(o1);
                o2 = gelu_f(o2); o3 = gelu_f(o3);
            }
            if (ADD_RES) {
                const float4 rv = *(const float4*)&R[grow];
                o0 += rv.x; o1 += rv.y; o2 += rv.z; o3 += rv.w;
            }
            if (OUT_BF16) {
                ushort4 pk;
                pk.x = f2bf(o0); pk.y = f2bf(o1);
                pk.z = f2bf(o2); pk.w = f2bf(o3);
                *(ushort4*)((unsigned short*)C + grow) = pk;
            } else {
                *(float4*)((float*)C + grow) = make_float4(o0, o1, o2, o3);
            }
        }
    }
}

// ---------------------------------------------------------------------------
// Fused GEMM(+bias+residual)+LayerNorm for N=512 shapes.
// Hout/Hb = LN(A@WT + bias + R)*g+be.  M mult 64, K mult 64.
// ROUND 6: wave layout 2Mx4N -> 1Mx8N (wave-tile 64x64, acc[4][4]).
// Old layout read 2A+8B ds_read_b128 per 16 MFMA (ratio 1.6, 80 reads/
// body/block -> ~960 LDS-pipe cyc vs ~155 MFMA cyc: LDS-read-bound at
// 1 block/CU). New: 4A+4B per 16 MFMA (64 reads/body, -20% on the bound
// pipe). Staging, swizzles, and the counted-vmcnt ledger are UNCHANGED:
//   prologue issue 9, vmcnt(4); bodyA issue 5, vmcnt(4); bodyB issue 4,
//   vmcnt(4); tail vmcnt(0). Epilogue now a single 64-row chunk:
//   Ef[64][516] fp32 (132KB < 147KB smem).
// In-place R==Hout safe: block reads R only for its own 64 rows, strictly
// before writing them.
// ---------------------------------------------------------------------------
__global__ __launch_bounds__(512, 1)
void gemm_ln_k(const __hip_bfloat16* __restrict__ A,
               const __hip_bfloat16* __restrict__ WT,
               const float* __restrict__ bias,
               const float* R,                    // no restrict: aliases Hout
               const float* __restrict__ g,
               const float* __restrict__ be,
               float* Hout,                       // no restrict: aliases R
               __hip_bfloat16* __restrict__ Hb,
               int K) {
    __shared__ __align__(16) char smem[147456];
    const int tid  = threadIdx.x;
    const int lane = tid & 63;
    const int wave = tid >> 6;

    // XCD swizzle (grid = 256 = 32 per XCD, bijective)
    const int Lid = blockIdx.x;
    const int m0 = ((Lid & 7) * 32 + (Lid >> 3)) * 64;

    const int r = lane & 15, q = lane >> 4;
    const int qaB  = (q ^ ((r >> 1) & 3)) * 8;   // B de-swizzle (32-short rows)
    const int qaA0 = ((q)     ^ (r & 7)) * 8;    // A ks0 (64-short rows)
    const int qaA1 = ((4 + q) ^ (r & 7)) * 8;    // A ks1
    const int wn = wave * 64;                    // wave's 64-column slab

    // staging addresses (pre-swizzled sources, linear LDS dests) — unchanged
    const int arow = tid >> 3;
    const int asb  = ((tid & 7) ^ ((tid >> 3) & 7)) * 8;
    const short* Ag = (const short*)A + (long)(m0 + arow) * K + asb;
    const int brow = tid >> 2;
    const int bsb  = ((tid & 3) ^ ((tid >> 3) & 3)) * 8;
    const short* Bg = (const short*)WT + (long)brow * K + bsb;
    const long brs = (long)128 * K;

    floatx4 acc[4][4];
    #pragma unroll
    for (int i = 0; i < 4; i++)
        #pragma unroll
        for (int j = 0; j < 4; j++) acc[i][j] = (floatx4)0.f;

    const int NTT = K >> 6;

    // prologue: tile 0 (A, Bks0, Bks1 = 9 loads/thread)
    {
        char* base = smem;
        async16(Ag, base + tid * 16);
        const short* p0 = Bg;
        char* d0 = base + 8192 + tid * 16;
        async16(p0, d0); async16(p0 + brs, d0 + 8192);
        async16(p0 + 2 * brs, d0 + 16384); async16(p0 + 3 * brs, d0 + 24576);
        const short* p1 = Bg + 32;
        char* d1 = base + 40960 + tid * 16;
        async16(p1, d1); async16(p1 + brs, d1 + 8192);
        async16(p1 + 2 * brs, d1 + 16384); async16(p1 + 3 * brs, d1 + 24576);
    }
    asm volatile("s_waitcnt vmcnt(4)" ::: "memory");  // A0 + B0ks0 landed
    __builtin_amdgcn_s_barrier();
    __builtin_amdgcn_sched_barrier(0);

    for (int t = 0; t < NTT; ++t) {
        const int cur = t & 1, nxt = cur ^ 1;
        const bool hn = (t + 1 < NTT);
        const short* As  = (const short*)(smem + cur * 73728);
        const short* B0s = (const short*)(smem + cur * 73728 + 8192);
        const short* B1s = (const short*)(smem + cur * 73728 + 40960);
        char* nb = smem + nxt * 73728;
        const long k1 = (long)(t + 1) * 64;

        // ---- body A: ks0 ----
        if (hn) {
            async16(Ag + k1, nb + tid * 16);                 // A(t+1): 1
            const short* p0 = Bg + k1;                       // Bks0(t+1): 4
            char* d0 = nb + 8192 + tid * 16;
            async16(p0, d0); async16(p0 + brs, d0 + 8192);
            async16(p0 + 2 * brs, d0 + 16384); async16(p0 + 3 * brs, d0 + 24576);
        }
        {
            short8 a[4], b[4];
            #pragma unroll
            for (int mf = 0; mf < 4; mf++)
                a[mf] = *(const short8*)&As[(mf * 16 + r) * 64 + qaA0];
            #pragma unroll
            for (int nf = 0; nf < 4; nf++)
                b[nf] = *(const short8*)&B0s[(wn + nf * 16 + r) * 32 + qaB];
            #pragma unroll
            for (int mf = 0; mf < 4; mf++)
                #pragma unroll
                for (int nf = 0; nf < 4; nf++)
                    acc[mf][nf] = __builtin_amdgcn_mfma_f32_16x16x32_bf16(
                        a[mf], b[nf], acc[mf][nf], 0, 0, 0);
        }
        __builtin_amdgcn_sched_barrier(0);
        if (hn) asm volatile("s_waitcnt vmcnt(4)" ::: "memory"); // Bks1(t)+A(t+1) in
        else    asm volatile("s_waitcnt vmcnt(0)" ::: "memory");
        __builtin_amdgcn_s_barrier();
        __builtin_amdgcn_sched_barrier(0);

        // ---- body B: ks1 ----
        if (hn) {
            const short* p1 = Bg + k1 + 32;                  // Bks1(t+1): 4
            char* d1 = nb + 40960 + tid * 16;
            async16(p1, d1); async16(p1 + brs, d1 + 8192);
            async16(p1 + 2 * brs, d1 + 16384); async16(p1 + 3 * brs, d1 + 24576);
        }
        {
            short8 a[4], b[4];
            #pragma unroll
            for (int mf = 0; mf < 4; mf++)
                a[mf] = *(const short8*)&As[(mf * 16 + r) * 64 + qaA1];
            #pragma unroll
            for (int nf = 0; nf < 4; nf++)
                b[nf] = *(const short8*)&B1s[(wn + nf * 16 + r) * 32 + qaB];
            #pragma unroll
            for (int mf = 0; mf < 4; mf++)
                #pragma unroll
                for (int nf = 0; nf < 4; nf++)
                    acc[mf][nf] = __builtin_amdgcn_mfma_f32_16x16x32_bf16(
                        a[mf], b[nf], acc[mf][nf], 0, 0, 0);
        }
        __builtin_amdgcn_sched_barrier(0);
        if (hn) asm volatile("s_waitcnt vmcnt(4)" ::: "memory"); // Bks0(t+1) in
        __builtin_amdgcn_s_barrier();
        __builtin_amdgcn_sched_barrier(0);
    }

    // ---- fused epilogue: restage -> +bias+R -> row LN stats -> store ----
    // Ef[64][516] fp32 (132096B; stride 516: rows spaced 4 banks; writer
    // rows q*4 spaced 2064 words = 16 banks -> 2-way max = free). stat after.
    float* Ef = (float*)smem;
    float* stat = (float*)(smem + 132096);
    const float gl = g[tid], bl = be[tid], bv = bias[tid];

    // write: wave w owns cols wn..wn+63 of ALL 64 rows (disjoint by column)
    #pragma unroll
    for (int mf = 0; mf < 4; mf++)
        #pragma unroll
        for (int nf = 0; nf < 4; nf++)
            #pragma unroll
            for (int rg = 0; rg < 4; rg++)
                Ef[(mf * 16 + q * 4 + rg) * 516 + wn + nf * 16 + r] =
                    acc[mf][nf][rg];
    __syncthreads();
    // bias + residual, coalesced (thread t owns column t of 64 rows)
    #pragma unroll 8
    for (int k = 0; k < 64; k++)
        Ef[k * 516 + tid] += bv + R[(long)(m0 + k) * 512 + tid];
    __syncthreads();
    // per-row stats: 8 threads per row, 64 cols each
    {
        const int row = tid >> 3, cc = tid & 7;
        float s = 0.f, ss = 0.f;
        #pragma unroll 8
        for (int j = 0; j < 64; j++) {
            const float v = Ef[row * 516 + cc + 8 * j];
            s += v; ss += v * v;
        }
        #pragma unroll
        for (int off = 1; off < 8; off <<= 1) {
            s  += __shfl_xor(s, off);
            ss += __shfl_xor(ss, off);
        }
        const float mu  = s * (1.0f / 512.0f);
        const float var = fmaxf(ss * (1.0f / 512.0f) - mu * mu, 0.f);
        const float inv = 1.0f / sqrtf(var + 1e-5f);
        if (cc == 0) { stat[row * 2] = mu; stat[row * 2 + 1] = inv; }
    }
    __syncthreads();
    // normalize + store, coalesced
    #pragma unroll 8
    for (int k = 0; k < 64; k++) {
        const float v  = Ef[k * 516 + tid];
        const float o  = (v - stat[k * 2]) * stat[k * 2 + 1] * gl + bl;
        const long idx = (long)(m0 + k) * 512 + tid;
        Hout[idx] = o;
        ((unsigned short*)Hb)[idx] = f2bf(o);
    }
}

// ---------------------------------------------------------------------------
// WT[l][n][k] = (bf16) W[l][k][n]
// ---------------------------------------------------------------------------
__global__ __launch_bounds__(256)
void transpose_cast_k(const float* __restrict__ W, __hip_bfloat16* __restrict__ WT,
                      int K, int N) {
    __shared__ float tile[32][33];
    const float* Wl = W + (long)blockIdx.z * K * N;
    __hip_bfloat16* WTl = WT + (long)blockIdx.z * K * N;
    const int n0 = blockIdx.x * 32, k0 = blockIdx.y * 32;
    const int tx = threadIdx.x & 31, ty = threadIdx.x >> 5;
    for (int rr = ty; rr < 32; rr += 8)
        tile[rr][tx] = Wl[(long)(k0 + rr) * N + n0 + tx];
    __syncthreads();
    for (int rr = ty; rr < 32; rr += 8)
        WTl[(long)(n0 + rr) * K + k0 + tx] = __float2bfloat16(tile[tx][rr]);
}

// ---------------------------------------------------------------------------
// fp32 tiled GEMM (in-proj only: M=16384, N=512, K=32)
// ---------------------------------------------------------------------------
template<int DO_GELU>
__global__ __launch_bounds__(256)
void gemm_bias_k(const float* __restrict__ A, long lda,
                 const float* __restrict__ W,
                 const float* __restrict__ bias,
                 float* __restrict__ C,
                 int M, int N, int K) {
    __shared__ float As[16][64];
    __shared__ float Ws[16][64];
    const int tx = threadIdx.x;
    const int ty = threadIdx.y;
    const int tid = ty * 16 + tx;
    const int m0 = blockIdx.y * 64;
    const int n0 = blockIdx.x * 64;
    float acc[4][4] = {};
    for (int k0 = 0; k0 < K; k0 += 16) {
        #pragma unroll
        for (int e = tid; e < 64 * 16; e += 256) {
            int m = e >> 4, k = e & 15;
            float v = 0.f;
            if (m0 + m < M) v = A[(long)(m0 + m) * lda + k0 + k];
            As[k][m] = v;
        }
        #pragma unroll
        for (int e = tid; e < 16 * 64; e += 256) {
            int k = e >> 6, n = e & 63;
            float v = 0.f;
            if (n0 + n < N) v = W[(long)(k0 + k) * N + n0 + n];
            Ws[k][n] = v;
        }
        __syncthreads();
        #pragma unroll
        for (int kk = 0; kk < 16; kk++) {
            float a[4], w[4];
            #pragma unroll
            for (int i = 0; i < 4; i++) a[i] = As[kk][ty * 4 + i];
            #pragma unroll
            for (int j = 0; j < 4; j++) w[j] = Ws[kk][tx * 4 + j];
            #pragma unroll
            for (int i = 0; i < 4; i++)
                #pragma unroll
                for (int j = 0; j < 4; j++)
                    acc[i][j] += a[i] * w[j];
        }
        __syncthreads();
    }
    #pragma unroll
    for (int i = 0; i < 4; i++) {
        int m = m0 + ty * 4 + i;
        if (m >= M) continue;
        #pragma unroll
        for (int j = 0; j < 4; j++) {
            int n = n0 + tx * 4 + j;
            if (n >= N) continue;
            float v = acc[i][j] + bias[n];
            if (DO_GELU) v = gelu_f(v);
            C[(long)m * N + n] = v;
        }
    }
}

// ---------------------------------------------------------------------------
// h = gelu(layernorm(X)) + pe ; also bf16 copy hb  (runs once)
// ---------------------------------------------------------------------------
__global__ __launch_bounds__(256)
void ln_gelu_pos_k(const float* __restrict__ X,
                   const float* __restrict__ g,
                   const float* __restrict__ be,
                   float* __restrict__ Hout,
                   __hip_bfloat16* __restrict__ Hb) {
    const int row = blockIdx.x;
    const int s = row & (S_ - 1);
    const int t = threadIdx.x;
    const float* x = X + (long)row * D_;
    float v0 = x[t], v1 = x[t + 256];
    __shared__ float red[256];
    red[t] = v0 + v1;
    __syncthreads();
    for (int off = 128; off; off >>= 1) {
        if (t < off) red[t] += red[t + off];
        __syncthreads();
    }
    float mu = red[0] * (1.0f / D_);
    __syncthreads();
    float d0 = v0 - mu, d1 = v1 - mu;
    red[t] = d0 * d0 + d1 * d1;
    __syncthreads();
    for (int off = 128; off; off >>= 1) {
        if (t < off) red[t] += red[t + off];
        __syncthreads();
    }
    float var = red[0] * (1.0f / D_);
    float inv = 1.0f / sqrtf(var + 1e-5f);
    float o0 = gelu_f(d0 * inv * g[t] + be[t]);
    float o1 = gelu_f(d1 * inv * g[t + 256] + be[t + 256]);
    {
        int d = t, i = d >> 1;
        float dv = expf((float)(2 * i) * (-9.210340371976184f / 512.0f));
        float ang = (float)s * dv;
        o0 += (d & 1) ? cosf(ang) : sinf(ang);
    }
    {
        int d = t + 256, i = d >> 1;
        float dv = expf((float)(2 * i) * (-9.210340371976184f / 512.0f));
        float ang = (float)s * dv;
        o1 += (d & 1) ? cosf(ang) : sinf(ang);
    }
    Hout[(long)row * D_ + t] = o0;
    Hout[(long)row * D_ + t + 256] = o1;
    Hb[(long)row * D_ + t] = __float2bfloat16(o0);
    Hb[(long)row * D_ + t + 256] = __float2bfloat16(o1);
}

// ---------------------------------------------------------------------------
// MFMA flash attention (verified structure, unchanged)
// ---------------------------------------------------------------------------
#define LDT 72
__global__ __launch_bounds__(256)
void attn_mfma_k(const __hip_bfloat16* __restrict__ qkv,
                 __hip_bfloat16* __restrict__ O) {
    const int qt = blockIdx.x;
    const int bh = blockIdx.y;
    const int b = bh >> 3, h = bh & (H_ - 1);
    const int tid = threadIdx.x;
    const int wave = tid >> 6, lane = tid & 63;
    const int ln = lane & 15, quad = lane >> 4;
    const int wm = wave * 32;
    const int i0 = qt * 128;

    __shared__ unsigned short Qs[128 * LDT];
    __shared__ unsigned short Ks[64 * LDT];
    __shared__ unsigned short Vt[64 * LDT];
    __shared__ unsigned short Ps[128 * LDT];
    __shared__ float stat[128];

    const unsigned short* base = (const unsigned short*)qkv + (long)b * S_ * (3 * D_);

    {
        const int r0 = tid >> 3, c0 = (tid & 7) * 8;
        #pragma unroll
        for (int i = 0; i < 4; i++) {
            const int rw = i * 32 + r0;
            *(short8*)&Qs[rw * LDT + c0] =
                *(const short8*)(base + (long)(i0 + rw) * (3 * D_) + h * HD_ + c0);
        }
    }

    float m_i[2] = { -INFINITY, -INFINITY };
    float l_i[2] = { 0.f, 0.f };
    floatx4 o_acc[2][4];
    #pragma unroll
    for (int i = 0; i < 2; i++)
        #pragma unroll
        for (int j = 0; j < 4; j++) o_acc[i][j] = (floatx4)0.f;

    const int kr = tid >> 2, kc = (tid & 3) * 16;
    const int vj = tid & 63, vc = (tid >> 6) * 16;

    const int ktmax = 2 * qt + 1;
    for (int kt = 0; kt <= ktmax; kt++) {
        const int j0 = kt * 64;
        {
            const unsigned short* kp = base + (long)(j0 + kr) * (3 * D_) + D_ + h * HD_ + kc;
            *(short8*)&Ks[kr * LDT + kc]     = *(const short8*)(kp);
            *(short8*)&Ks[kr * LDT + kc + 8] = *(const short8*)(kp + 8);
            const unsigned short* vp = base + (long)(j0 + vj) * (3 * D_) + 2 * D_ + h * HD_ + vc;
            short8 v0 = *(const short8*)(vp);
            short8 v1 = *(const short8*)(vp + 8);
            #pragma unroll
            for (int e = 0; e < 8; e++) {
                Vt[(vc + e) * LDT + vj]     = (unsigned short)v0[e];
                Vt[(vc + 8 + e) * LDT + vj] = (unsigned short)v1[e];
            }
        }
        __syncthreads();

        floatx4 sa[4][2];
        #pragma unroll
        for (int mt = 0; mt < 4; mt++)
            #pragma unroll
            for (int nt = 0; nt < 2; nt++) sa[mt][nt] = (floatx4)0.f;
        #pragma unroll
        for (int c = 0; c < 2; c++) {
            short8 kf[4], qf[2];
            #pragma unroll
            for (int mt = 0; mt < 4; mt++)
                kf[mt] = *(const short8*)&Ks[(mt * 16 + ln) * LDT + c * 32 + quad * 8];
            #pragma unroll
            for (int nt = 0; nt < 2; nt++)
                qf[nt] = *(const short8*)&Qs[(wm + nt * 16 + ln) * LDT + c * 32 + quad * 8];
            #pragma unroll
            for (int mt = 0; mt < 4; mt++)
                #pragma unroll
                for (int nt = 0; nt < 2; nt++)
                    sa[mt][nt] = __builtin_amdgcn_mfma_f32_16x16x32_bf16(
                        kf[mt], qf[nt], sa[mt][nt], 0, 0, 0);
        }

        const bool domask = (kt >= 2 * qt);
        #pragma unroll
        for (int nt = 0; nt < 2; nt++) {
            const int qg = i0 + wm + nt * 16 + ln;
            float mx = -INFINITY;
            #pragma unroll
            for (int mt = 0; mt < 4; mt++)
                #pragma unroll
                for (int rg = 0; rg < 4; rg++) {
                    float v = sa[mt][nt][rg] * 0.125f;
                    if (domask && (j0 + mt * 16 + quad * 4 + rg > qg)) v = -INFINITY;
                    sa[mt][nt][rg] = v;
                    mx = fmaxf(mx, v);
                }
            mx = fmaxf(mx, __shfl_xor(mx, 16));
            mx = fmaxf(mx, __shfl_xor(mx, 32));
            const float mn = fmaxf(m_i[nt], mx);
            const float alpha = __expf(m_i[nt] - mn);
            m_i[nt] = mn;
            float ls = 0.f;
            #pragma unroll
            for (int mt = 0; mt < 4; mt++) {
                ushort4 pk;
                float p0 = __expf(sa[mt][nt][0] - mn);
                float p1 = __expf(sa[mt][nt][1] - mn);
                float p2 = __expf(sa[mt][nt][2] - mn);
                float p3 = __expf(sa[mt][nt][3] - mn);
                ls += p0 + p1 + p2 + p3;
                pk.x = f2bf(p0); pk.y = f2bf(p1); pk.z = f2bf(p2); pk.w = f2bf(p3);
                *(ushort4*)&Ps[(wm + nt * 16 + ln) * LDT + mt * 16 + quad * 4] = pk;
            }
            ls += __shfl_xor(ls, 16);
            ls += __shfl_xor(ls, 32);
            l_i[nt] = l_i[nt] * alpha + ls;
            if (quad == 0) stat[wm + nt * 16 + ln] = alpha;
        }

        #pragma unroll
        for (int mt2 = 0; mt2 < 2; mt2++) {
            #pragma unroll
            for (int rg = 0; rg < 4; rg++) {
                const float a = stat[wm + mt2 * 16 + quad * 4 + rg];
                #pragma unroll
                for (int nt = 0; nt < 4; nt++) o_acc[mt2][nt][rg] *= a;
            }
        }

        #pragma unroll
        for (int c = 0; c < 2; c++) {
            short8 pf[2], vf[4];
            #pragma unroll
            for (int mt2 = 0; mt2 < 2; mt2++)
                pf[mt2] = *(const short8*)&Ps[(wm + mt2 * 16 + ln) * LDT + c * 32 + quad * 8];
            #pragma unroll
            for (int nt = 0; nt < 4; nt++)
                vf[nt] = *(const short8*)&Vt[(nt * 16 + ln) * LDT + c * 32 + quad * 8];
            #pragma unroll
            for (int mt2 = 0; mt2 < 2; mt2++)
                #pragma unroll
                for (int nt = 0; nt < 4; nt++)
                    o_acc[mt2][nt] = __builtin_amdgcn_mfma_f32_16x16x32_bf16(
                        pf[mt2], vf[nt], o_acc[mt2][nt], 0, 0, 0);
        }
        __syncthreads();
    }

    if (quad == 0) {
        stat[wm + ln]      = l_i[0];
        stat[wm + 16 + ln] = l_i[1];
    }
    unsigned short* Og = (unsigned short*)O;
    #pragma unroll
    for (int mt2 = 0; mt2 < 2; mt2++) {
        #pragma unroll
        for (int rg = 0; rg < 4; rg++) {
            const float linv = 1.0f / stat[wm + mt2 * 16 + quad * 4 + rg];
            const long row = (long)(b * S_ + i0 + wm + mt2 * 16 + quad * 4 + rg);
            #pragma unroll
            for (int nt = 0; nt < 4; nt++)
                Og[row * D_ + h * HD_ + nt * 16 + ln] =
                    f2bf(o_acc[mt2][nt][rg] * linv);
        }
    }
}

// ---------------------------------------------------------------------------
// Head kernels
// ---------------------------------------------------------------------------
__global__ __launch_bounds__(256)
void head1_k(const float* __restrict__ h, const float* __restrict__ w1,
             const float* __restrict__ b1, float* __restrict__ th) {
    __shared__ float hs[D_];
    const int b = blockIdx.x, n = threadIdx.x;
    const float* hr = h + (long)(b * S_ + S_ - 1) * D_;
    hs[n] = hr[n];
    hs[n + 256] = hr[n + 256];
    __syncthreads();
    float s = 0.f;
    #pragma unroll 8
    for (int k = 0; k < D_; k++) s += hs[k] * w1[(long)k * 256 + n];
    th[b * 256 + n] = gelu_f(s + b1[n]);
}

__global__ __launch_bounds__(64)
void head2_k(const float* __restrict__ th, const float* __restrict__ w2,
             const float* __restrict__ b2, float* __restrict__ out) {
    const int b = blockIdx.x, lane = threadIdx.x;
    const float* t = th + b * 256;
    float s0 = 0.f, s1 = 0.f, s2 = 0.f;
    #pragma unroll
    for (int e = 0; e < 4; e++) {
        const int k = lane * 4 + e;
        const float tv = t[k];
        s0 += tv * w2[k * 3 + 0];
        s1 += tv * w2[k * 3 + 1];
        s2 += tv * w2[k * 3 + 2];
    }
    #pragma unroll
    for (int off = 1; off < 64; off <<= 1) {
        s0 += __shfl_xor(s0, off);
        s1 += __shfl_xor(s1, off);
        s2 += __shfl_xor(s2, off);
    }
    if (lane == 0) {
        out[b * 3 + 0] = s0 + b2[0];
        out[b * 3 + 1] = s1 + b2[1];
        out[b * 3 + 2] = s2 + b2[2];
    }
}

// ---------------------------------------------------------------------------
extern "C" void kernel_launch(void* const* d_in, const int* in_sizes, int n_in,
                              void* d_out, int out_size, void* d_ws, size_t ws_size,
                              hipStream_t stream) {
    const float* x     = (const float*)d_in[0];
    const float* w_in  = (const float*)d_in[1];
    const float* b_in  = (const float*)d_in[2];
    const float* g_in  = (const float*)d_in[3];
    const float* be_in = (const float*)d_in[4];
    const float* w_qkv = (const float*)d_in[5];
    const float* b_qkv = (const float*)d_in[6];
    const float* w_out = (const float*)d_in[7];
    const float* b_out = (const float*)d_in[8];
    const float* g1    = (const float*)d_in[9];
    const float* be1   = (const float*)d_in[10];
    const float* w_ff1 = (const float*)d_in[11];
    const float* b_ff1 = (const float*)d_in[12];
    const float* w_ff2 = (const float*)d_in[13];
    const float* b_ff2 = (const float*)d_in[14];
    const float* g2    = (const float*)d_in[15];
    const float* be2   = (const float*)d_in[16];
    const float* w_h1  = (const float*)d_in[17];
    const float* b_h1  = (const float*)d_in[18];
    const float* w_h2  = (const float*)d_in[19];
    const float* b_h2  = (const float*)d_in[20];
    float* out = (float*)d_out;

    float* h    = (float*)d_ws;
    float* bufB = h + (long)M_ * D_;
    float* th   = bufB + (long)M_ * D_;
    __hip_bfloat16* hb    = (__hip_bfloat16*)(th + 32 * 256);
    __hip_bfloat16* attb  = hb + (long)M_ * D_;
    __hip_bfloat16* bufAb = attb + (long)M_ * D_;
    __hip_bfloat16* qkvT  = bufAb + (long)M_ * FF_;
    __hip_bfloat16* outT  = qkvT + (long)L_ * (3 * D_) * D_;
    __hip_bfloat16* ff1T  = outT + (long)L_ * D_ * D_;
    __hip_bfloat16* ff2T  = ff1T + (long)L_ * FF_ * D_;

    dim3 blk(16, 16);

    transpose_cast_k<<<dim3((3 * D_) / 32, D_ / 32, L_), 256, 0, stream>>>(w_qkv, qkvT, D_, 3 * D_);
    transpose_cast_k<<<dim3(D_ / 32, D_ / 32, L_), 256, 0, stream>>>(w_out, outT, D_, D_);
    transpose_cast_k<<<dim3(FF_ / 32, D_ / 32, L_), 256, 0, stream>>>(w_ff1, ff1T, D_, FF_);
    transpose_cast_k<<<dim3(D_ / 32, FF_ / 32, L_), 256, 0, stream>>>(w_ff2, ff2T, FF_, D_);

    gemm_bias_k<0><<<dim3(D_ / 64, M_ / 64), blk, 0, stream>>>(
        x, IN_, w_in, b_in, bufB, M_, D_, IN_);
    ln_gelu_pos_k<<<M_, 256, 0, stream>>>(bufB, g_in, be_in, h, hb);

    for (int l = 0; l < L_; l++) {
        // qkv -> bf16 bufAb (128^2 counted-vmcnt, 1536 blocks)
        gemm_mfma_k<0, 1, 0><<<dim3((3 * D_) / 128, M_ / 128), 256, 0, stream>>>(
            hb, qkvT + (long)l * (3 * D_) * D_, b_qkv + l * 3 * D_, nullptr,
            bufAb, 3 * D_, D_);
        attn_mfma_k<<<dim3(S_ / 128, B_ * H_), 256, 0, stream>>>(bufAb, attb);
        // fused: h = LN(attb @ outT + b_out + h)  (writes h fp32 + hb bf16)
        gemm_ln_k<<<256, 512, 0, stream>>>(
            attb, outT + (long)l * D_ * D_, b_out + l * D_, h,
            g1 + l * D_, be1 + l * D_, h, hb, D_);
        // ff1 -> bf16 bufAb (gelu)  (128^2 counted-vmcnt, 2048 blocks, 2/CU)
        gemm_mfma_k<1, 1, 0><<<dim3(FF_ / 128, M_ / 128), 256, 0, stream>>>(
            hb, ff1T + (long)l * FF_ * D_, b_ff1 + l * FF_, nullptr,
            bufAb, FF_, D_);
        // fused: h = LN(bufAb @ ff2T + b_ff2 + h)
        gemm_ln_k<<<256, 512, 0, stream>>>(
            bufAb, ff2T + (long)l * D_ * FF_, b_ff2 + l * D_, h,
            g2 + l * D_, be2 + l * D_, h, hb, FF_);
    }

    head1_k<<<B_, 256, 0, stream>>>(h, w_h1, b_h1, th);
    head2_k<<<B_, 64, 0, stream>>>(th, w_h2, b_h2, out);
}

// Round 7
// 1585.732 us; speedup vs baseline: 1.0642x; 1.0041x over previous
//
#include <hip/hip_runtime.h>
#include <hip/hip_bf16.h>
#include <math.h>

#define D_   512
#define H_   8
#define HD_  64
#define L_   6
#define FF_  2048
#define IN_  32
#define OUT_ 3
#define S_   512
#define B_   32
#define M_   (B_ * S_)   // 16384 token rows

typedef __attribute__((ext_vector_type(8))) short short8;
typedef __attribute__((ext_vector_type(4))) float floatx4;

// Branchless gelu: 0.5x(1+erf(x/sqrt2)), erf via A&S 7.1.26 (max err 1.5e-7).
__device__ __forceinline__ float gelu_f(float x) {
    const float ax = fabsf(x) * 0.70710678118654752f;
    const float t = __builtin_amdgcn_rcpf(fmaf(0.3275911f, ax, 1.0f));
    float p = fmaf(1.061405429f, t, -1.453152027f);
    p = fmaf(p, t, 1.421413741f);
    p = fmaf(p, t, -0.284496736f);
    p = fmaf(p, t, 0.254829592f);
    p = p * t;
    const float e = __expf(-ax * ax);
    const float er = copysignf(fmaf(-p, e, 1.0f), x);
    return 0.5f * x * (1.0f + er);
}
__device__ __forceinline__ float bf2f(unsigned short u) {
    union { unsigned int i; float f; } c; c.i = ((unsigned)u) << 16; return c.f;
}
__device__ __forceinline__ unsigned short f2bf(float v) {
    __hip_bfloat16 t = __float2bfloat16(v);
    return *(unsigned short*)&t;
}
__device__ __forceinline__ void async16(const void* g, void* l) {
    __builtin_amdgcn_global_load_lds(
        (const __attribute__((address_space(1))) unsigned int*)g,
        (__attribute__((address_space(3))) unsigned int*)l, 16, 0, 0);
}
// one K-half stage step: 2 async16 (row srow and srow + rows/2)
__device__ __forceinline__ void stage2(const short* g, char* d, long rs, int off2) {
    async16(g, d);
    async16(g + rs, d + off2);
}

// ---------------------------------------------------------------------------
// Swizzle (T2, verified round 2: conflicts 4.19M -> 1.05M):
//   read col-block  qa = (q ^ ((r>>1)&3)) * 8 shorts   (32-short rows)
//   stage col-block sc = ((tid&3) ^ ((tid>>3)&3)) * 8 shorts
// 64-short rows (gemm_ln_k A): qa = ((ks*4+q) ^ (r&7))*8, src (t&7)^((t>>3)&7)
// ---------------------------------------------------------------------------

// ---------------------------------------------------------------------------
// bf16 MFMA GEMM 128x128, counted-vmcnt 2-body ledger (round-2 verified;
// 64KB LDS -> 2 blocks/CU). Ledger re-audited r7: its waits retire only
// loads issued >= 1 full body earlier — no premature-retire hole. UNCHANGED.
// ---------------------------------------------------------------------------
template<int DO_GELU, int OUT_BF16, int ADD_RES>
__global__ __launch_bounds__(256, 2)
void gemm_mfma_k(const __hip_bfloat16* __restrict__ A,
                 const __hip_bfloat16* __restrict__ WT,
                 const float* __restrict__ bias,
                 const float* __restrict__ R,
                 void* __restrict__ C,
                 int N, int K) {
    __shared__ __align__(16) char smem[65536];
    float* Ep = (float*)smem;

    const int tid  = threadIdx.x;
    const int lane = tid & 63;
    const int wave = tid >> 6;

    const int Lid = blockIdx.y * gridDim.x + blockIdx.x;
    const int xcd = Lid & 7;
    const int idx = Lid >> 3;
    const int gx  = gridDim.x, gy8 = gridDim.y >> 3;
    const int m0 = (xcd * gy8 + idx / gx) * 128;
    const int n0 = (idx % gx) * 128;

    const int wm = (wave >> 1) * 64, wn = (wave & 1) * 64;
    const int r = lane & 15, q = lane >> 4;
    const int qa = (q ^ ((r >> 1) & 3)) * 8;   // T2-fixed de-swizzle

    const int srow = tid >> 2;                 // 0..63
    const int sc = ((tid & 3) ^ ((tid >> 3) & 3)) * 8;
    const short* Ag = (const short*)A + (long)(m0 + srow) * K + sc;
    const short* Bg = (const short*)WT + (long)(n0 + srow) * K + sc;
    const long rs = (long)64 * K;              // +64 rows (shorts)

    floatx4 acc[4][4];
    #pragma unroll
    for (int i = 0; i < 4; i++)
        #pragma unroll
        for (int j = 0; j < 4; j++) acc[i][j] = (floatx4)0.f;

    const int NT = K >> 6;

    stage2(Ag,      smem + 0     + tid * 16, rs, 4096);
    stage2(Bg,      smem + 16384 + tid * 16, rs, 4096);
    stage2(Ag + 32, smem + 8192  + tid * 16, rs, 4096);
    stage2(Bg + 32, smem + 24576 + tid * 16, rs, 4096);
    asm volatile("s_waitcnt vmcnt(4)" ::: "memory");  // ks0 landed
    __builtin_amdgcn_s_barrier();
    __builtin_amdgcn_sched_barrier(0);

    short8 a[4], b[4];
    for (int t = 0; t < NT; ++t) {
        const int cur = t & 1, nxt = cur ^ 1;
        const bool hn = (t + 1 < NT);
        const short* As = (const short*)(smem + cur * 32768);
        const short* Bs = (const short*)(smem + cur * 32768 + 16384);
        const short* Agt = Ag + (t + 1) * 64;
        const short* Bgt = Bg + (t + 1) * 64;
        char* Ad = smem + nxt * 32768;
        char* Bd = smem + nxt * 32768 + 16384;

        // ---- body A: ks0 ----
        if (hn) {
            stage2(Agt, Ad + tid * 16, rs, 4096);
            stage2(Bgt, Bd + tid * 16, rs, 4096);
        }
        #pragma unroll
        for (int i = 0; i < 4; i++)
            a[i] = *(const short8*)&As[(wm + i * 16 + r) * 32 + qa];
        #pragma unroll
        for (int j = 0; j < 4; j++)
            b[j] = *(const short8*)&Bs[(wn + j * 16 + r) * 32 + qa];
        #pragma unroll
        for (int i = 0; i < 4; i++)
            #pragma unroll
            for (int j = 0; j < 4; j++)
                acc[i][j] = __builtin_amdgcn_mfma_f32_16x16x32_bf16(
                    a[i], b[j], acc[i][j], 0, 0, 0);
        __builtin_amdgcn_sched_barrier(0);
        if (hn) asm volatile("s_waitcnt vmcnt(4)" ::: "memory");
        else    asm volatile("s_waitcnt vmcnt(0)" ::: "memory");
        __builtin_amdgcn_s_barrier();
        __builtin_amdgcn_sched_barrier(0);

        // ---- body B: ks1 ----
        if (hn) {
            stage2(Agt + 32, Ad + 8192 + tid * 16, rs, 4096);
            stage2(Bgt + 32, Bd + 8192 + tid * 16, rs, 4096);
        }
        #pragma unroll
        for (int i = 0; i < 4; i++)
            a[i] = *(const short8*)&As[4096 + (wm + i * 16 + r) * 32 + qa];
        #pragma unroll
        for (int j = 0; j < 4; j++)
            b[j] = *(const short8*)&Bs[4096 + (wn + j * 16 + r) * 32 + qa];
        #pragma unroll
        for (int i = 0; i < 4; i++)
            #pragma unroll
            for (int j = 0; j < 4; j++)
                acc[i][j] = __builtin_amdgcn_mfma_f32_16x16x32_bf16(
                    a[i], b[j], acc[i][j], 0, 0, 0);
        __builtin_amdgcn_sched_barrier(0);
        if (hn) asm volatile("s_waitcnt vmcnt(4)" ::: "memory");
        __builtin_amdgcn_s_barrier();
        __builtin_amdgcn_sched_barrier(0);
    }

    // ---- epilogue: restage through LDS, coalesced postprocess + store ----
    const int erow = tid >> 5;          // 0..7
    const int ecol = (tid & 31) * 4;    // 0..124, float4 granularity
    const float4 bvec = *(const float4*)&bias[n0 + ecol];

    #pragma unroll
    for (int pass = 0; pass < 2; pass++) {
        if (pass) __syncthreads();
        if ((wave >> 1) == pass) {
            #pragma unroll
            for (int i = 0; i < 4; i++)
                #pragma unroll
                for (int j = 0; j < 4; j++)
                    #pragma unroll
                    for (int rg = 0; rg < 4; rg++)
                        Ep[(i * 16 + q * 4 + rg) * 132 + wn + j * 16 + r] =
                            acc[i][j][rg];
        }
        __syncthreads();
        #pragma unroll
        for (int it = 0; it < 8; it++) {
            const int row = it * 8 + erow;
            const long grow = (long)(m0 + pass * 64 + row) * N + n0 + ecol;
            const float4 v = *(const float4*)&Ep[row * 132 + ecol];
            float o0 = v.x + bvec.x, o1 = v.y + bvec.y;
            float o2 = v.z + bvec.z, o3 = v.w + bvec.w;
            if (DO_GELU) {
                o0 = gelu_f(o0); o1 = gelu_f(o1);
                o2 = gelu_f(o2); o3 = gelu_f(o3);
            }
            if (ADD_RES) {
                const float4 rv = *(const float4*)&R[grow];
                o0 += rv.x; o1 += rv.y; o2 += rv.z; o3 += rv.w;
            }
            if (OUT_BF16) {
                ushort4 pk;
                pk.x = f2bf(o0); pk.y = f2bf(o1);
                pk.z = f2bf(o2); pk.w = f2bf(o3);
                *(ushort4*)((unsigned short*)C + grow) = pk;
            } else {
                *(float4*)((float*)C + grow) = make_float4(o0, o1, o2, o3);
            }
        }
    }
}

// ---------------------------------------------------------------------------
// Fused GEMM(+bias+residual)+LayerNorm for N=512 shapes.
// Hout/Hb = LN(A@WT + bias + R)*g+be.  M mult 64, K mult 64.
// ROUND 7: ledger fix + A prefetch distance 2.
//   R6's bodyA vmcnt(4) retired A(t+1) — issued at the START of that same
//   body (premature-retire: ~300-900cyc stall every bodyA, no co-resident
//   block to absorb at 1 block/CU). Fix: waits only ever retire loads >= 1
//   full body old. A (the streamed/L3-latency operand) now triple-slotted,
//   issued 2 tiles ahead.
// LDS 152KB: A slots 3x8KB @0/8192/16384; B bufs 2x64KB @24576 (+ks*32768).
// FIFO ledger (traced): prologue issue [Bks0(0):4, A(0):1, A(1):1,
//   Bks1(0):4] -> vmcnt(5) retires Bks0(0)+A(0).
//   bodyA(t): issue Bks0(t+1):4, A(t+2):1 -> read A(t)ks0,B(t)ks0 -> MFMA ->
//     vmcnt(5)  [retires A(t+1) (2 bodies old) + Bks1(t) (1 body old)]
//   bodyB(t): issue Bks1(t+1):4 -> read A(t)ks1,B(t)ks1 -> MFMA ->
//     vmcnt(5)  [retires Bks0(t+1) (1 body old); A(t+2) stays in flight]
// Tail: issues are UNIFORM via index clamp (redundant reloads land in
// slots never read: A slot (t+2)%3 != any later-read slot; B buf (t+1)&1
// != buf being read). After loop: vmcnt(0)+barrier drain BEFORE smem is
// reused as Ef (clamped loads may still be landing there).
// In-place R==Hout safe: block reads R only for its own 64 rows.
// ---------------------------------------------------------------------------
__global__ __launch_bounds__(512, 1)
void gemm_ln_k(const __hip_bfloat16* __restrict__ A,
               const __hip_bfloat16* __restrict__ WT,
               const float* __restrict__ bias,
               const float* R,                    // no restrict: aliases Hout
               const float* __restrict__ g,
               const float* __restrict__ be,
               float* Hout,                       // no restrict: aliases R
               __hip_bfloat16* __restrict__ Hb,
               int K) {
    __shared__ __align__(16) char smem[155648];
    const int tid  = threadIdx.x;
    const int lane = tid & 63;
    const int wave = tid >> 6;

    // XCD swizzle (grid = 256 = 32 per XCD, bijective)
    const int Lid = blockIdx.x;
    const int m0 = ((Lid & 7) * 32 + (Lid >> 3)) * 64;

    const int r = lane & 15, q = lane >> 4;
    const int qaB  = (q ^ ((r >> 1) & 3)) * 8;   // B de-swizzle (32-short rows)
    const int qaA0 = ((q)     ^ (r & 7)) * 8;    // A ks0 (64-short rows)
    const int qaA1 = ((4 + q) ^ (r & 7)) * 8;    // A ks1
    const int wn = wave * 64;                    // wave's 64-column slab

    // staging addresses (pre-swizzled sources, linear LDS dests)
    const int arow = tid >> 3;
    const int asb  = ((tid & 7) ^ ((tid >> 3) & 7)) * 8;
    const short* Ag = (const short*)A + (long)(m0 + arow) * K + asb;
    const int brow = tid >> 2;
    const int bsb  = ((tid & 3) ^ ((tid >> 3) & 3)) * 8;
    const short* Bg = (const short*)WT + (long)brow * K + bsb;
    const long brs = (long)128 * K;

    floatx4 acc[4][4];
    #pragma unroll
    for (int i = 0; i < 4; i++)
        #pragma unroll
        for (int j = 0; j < 4; j++) acc[i][j] = (floatx4)0.f;

    const int NTT = K >> 6;

    // issue helpers (offsets): A slot s at smem + s*8192; B at 24576 +
    // buf*65536 + ks*32768 (4 loads at +0/+8192/+16384/+24576 within half).
    // prologue: [Bks0(0):4, A(0):1, A(1):1, Bks1(0):4] -> vmcnt(5)
    {
        const short* p0 = Bg;
        char* d0 = smem + 24576 + tid * 16;
        async16(p0, d0); async16(p0 + brs, d0 + 8192);
        async16(p0 + 2 * brs, d0 + 16384); async16(p0 + 3 * brs, d0 + 24576);
        async16(Ag, smem + tid * 16);                          // A(0) slot 0
        const int t1 = (1 < NTT) ? 1 : (NTT - 1);
        async16(Ag + (long)t1 * 64, smem + 8192 + tid * 16);   // A(1) slot 1
        const short* p1 = Bg + 32;
        char* d1 = smem + 24576 + 32768 + tid * 16;
        async16(p1, d1); async16(p1 + brs, d1 + 8192);
        async16(p1 + 2 * brs, d1 + 16384); async16(p1 + 3 * brs, d1 + 24576);
    }
    asm volatile("s_waitcnt vmcnt(5)" ::: "memory");  // Bks0(0)+A(0) landed
    __builtin_amdgcn_s_barrier();
    __builtin_amdgcn_sched_barrier(0);

    int slotR = 0;                    // t % 3
    for (int t = 0; t < NTT; ++t) {
        const short* As  = (const short*)(smem + slotR * 8192);
        const short* B0s = (const short*)(smem + 24576 + (t & 1) * 65536);
        const short* B1s = B0s + 16384;   // +32768 bytes
        const int tp1 = (t + 1 < NTT) ? t + 1 : NTT - 1;   // clamped
        const int tp2 = (t + 2 < NTT) ? t + 2 : NTT - 1;   // clamped
        int slotW = slotR + 2; if (slotW >= 3) slotW -= 3;  // (t+2)%3

        // ---- body A: ks0 ----
        {
            const short* p0 = Bg + (long)tp1 * 64;           // Bks0(t+1): 4
            char* d0 = smem + 24576 + ((t + 1) & 1) * 65536 + tid * 16;
            async16(p0, d0); async16(p0 + brs, d0 + 8192);
            async16(p0 + 2 * brs, d0 + 16384); async16(p0 + 3 * brs, d0 + 24576);
            async16(Ag + (long)tp2 * 64, smem + slotW * 8192 + tid * 16); // A(t+2)
        }
        {
            short8 a[4], b[4];
            #pragma unroll
            for (int mf = 0; mf < 4; mf++)
                a[mf] = *(const short8*)&As[(mf * 16 + r) * 64 + qaA0];
            #pragma unroll
            for (int nf = 0; nf < 4; nf++)
                b[nf] = *(const short8*)&B0s[(wn + nf * 16 + r) * 32 + qaB];
            #pragma unroll
            for (int mf = 0; mf < 4; mf++)
                #pragma unroll
                for (int nf = 0; nf < 4; nf++)
                    acc[mf][nf] = __builtin_amdgcn_mfma_f32_16x16x32_bf16(
                        a[mf], b[nf], acc[mf][nf], 0, 0, 0);
        }
        __builtin_amdgcn_sched_barrier(0);
        asm volatile("s_waitcnt vmcnt(5)" ::: "memory"); // A(t+1)+Bks1(t) in
        __builtin_amdgcn_s_barrier();
        __builtin_amdgcn_sched_barrier(0);

        // ---- body B: ks1 ----
        {
            const short* p1 = Bg + (long)tp1 * 64 + 32;      // Bks1(t+1): 4
            char* d1 = smem + 24576 + ((t + 1) & 1) * 65536 + 32768 + tid * 16;
            async16(p1, d1); async16(p1 + brs, d1 + 8192);
            async16(p1 + 2 * brs, d1 + 16384); async16(p1 + 3 * brs, d1 + 24576);
        }
        {
            short8 a[4], b[4];
            #pragma unroll
            for (int mf = 0; mf < 4; mf++)
                a[mf] = *(const short8*)&As[(mf * 16 + r) * 64 + qaA1];
            #pragma unroll
            for (int nf = 0; nf < 4; nf++)
                b[nf] = *(const short8*)&B1s[(wn + nf * 16 + r) * 32 + qaB];
            #pragma unroll
            for (int mf = 0; mf < 4; mf++)
                #pragma unroll
                for (int nf = 0; nf < 4; nf++)
                    acc[mf][nf] = __builtin_amdgcn_mfma_f32_16x16x32_bf16(
                        a[mf], b[nf], acc[mf][nf], 0, 0, 0);
        }
        __builtin_amdgcn_sched_barrier(0);
        asm volatile("s_waitcnt vmcnt(5)" ::: "memory"); // Bks0(t+1) in
        __builtin_amdgcn_s_barrier();
        __builtin_amdgcn_sched_barrier(0);

        slotR = slotR + 1; if (slotR >= 3) slotR -= 3;
    }

    // drain clamped tail loads before smem is reused as Ef
    asm volatile("s_waitcnt vmcnt(0)" ::: "memory");
    __builtin_amdgcn_s_barrier();
    __builtin_amdgcn_sched_barrier(0);

    // ---- fused epilogue: restage -> +bias+R -> row LN stats -> store ----
    // Ef[64][516] fp32 (132096B; writer rows q*4 spaced 2064 words = 16
    // banks -> 2-way max = free). stat after.
    float* Ef = (float*)smem;
    float* stat = (float*)(smem + 132096);
    const float gl = g[tid], bl = be[tid], bv = bias[tid];

    // write: wave w owns cols wn..wn+63 of ALL 64 rows (disjoint by column)
    #pragma unroll
    for (int mf = 0; mf < 4; mf++)
        #pragma unroll
        for (int nf = 0; nf < 4; nf++)
            #pragma unroll
            for (int rg = 0; rg < 4; rg++)
                Ef[(mf * 16 + q * 4 + rg) * 516 + wn + nf * 16 + r] =
                    acc[mf][nf][rg];
    __syncthreads();
    // bias + residual, coalesced (thread t owns column t of 64 rows)
    #pragma unroll 8
    for (int k = 0; k < 64; k++)
        Ef[k * 516 + tid] += bv + R[(long)(m0 + k) * 512 + tid];
    __syncthreads();
    // per-row stats: 8 threads per row, 64 cols each
    {
        const int row = tid >> 3, cc = tid & 7;
        float s = 0.f, ss = 0.f;
        #pragma unroll 8
        for (int j = 0; j < 64; j++) {
            const float v = Ef[row * 516 + cc + 8 * j];
            s += v; ss += v * v;
        }
        #pragma unroll
        for (int off = 1; off < 8; off <<= 1) {
            s  += __shfl_xor(s, off);
            ss += __shfl_xor(ss, off);
        }
        const float mu  = s * (1.0f / 512.0f);
        const float var = fmaxf(ss * (1.0f / 512.0f) - mu * mu, 0.f);
        const float inv = 1.0f / sqrtf(var + 1e-5f);
        if (cc == 0) { stat[row * 2] = mu; stat[row * 2 + 1] = inv; }
    }
    __syncthreads();
    // normalize + store, coalesced
    #pragma unroll 8
    for (int k = 0; k < 64; k++) {
        const float v  = Ef[k * 516 + tid];
        const float o  = (v - stat[k * 2]) * stat[k * 2 + 1] * gl + bl;
        const long idx = (long)(m0 + k) * 512 + tid;
        Hout[idx] = o;
        ((unsigned short*)Hb)[idx] = f2bf(o);
    }
}

// ---------------------------------------------------------------------------
// WT[l][n][k] = (bf16) W[l][k][n]
// ---------------------------------------------------------------------------
__global__ __launch_bounds__(256)
void transpose_cast_k(const float* __restrict__ W, __hip_bfloat16* __restrict__ WT,
                      int K, int N) {
    __shared__ float tile[32][33];
    const float* Wl = W + (long)blockIdx.z * K * N;
    __hip_bfloat16* WTl = WT + (long)blockIdx.z * K * N;
    const int n0 = blockIdx.x * 32, k0 = blockIdx.y * 32;
    const int tx = threadIdx.x & 31, ty = threadIdx.x >> 5;
    for (int rr = ty; rr < 32; rr += 8)
        tile[rr][tx] = Wl[(long)(k0 + rr) * N + n0 + tx];
    __syncthreads();
    for (int rr = ty; rr < 32; rr += 8)
        WTl[(long)(n0 + rr) * K + k0 + tx] = __float2bfloat16(tile[tx][rr]);
}

// ---------------------------------------------------------------------------
// fp32 tiled GEMM (in-proj only: M=16384, N=512, K=32)
// ---------------------------------------------------------------------------
template<int DO_GELU>
__global__ __launch_bounds__(256)
void gemm_bias_k(const float* __restrict__ A, long lda,
                 const float* __restrict__ W,
                 const float* __restrict__ bias,
                 float* __restrict__ C,
                 int M, int N, int K) {
    __shared__ float As[16][64];
    __shared__ float Ws[16][64];
    const int tx = threadIdx.x;
    const int ty = threadIdx.y;
    const int tid = ty * 16 + tx;
    const int m0 = blockIdx.y * 64;
    const int n0 = blockIdx.x * 64;
    float acc[4][4] = {};
    for (int k0 = 0; k0 < K; k0 += 16) {
        #pragma unroll
        for (int e = tid; e < 64 * 16; e += 256) {
            int m = e >> 4, k = e & 15;
            float v = 0.f;
            if (m0 + m < M) v = A[(long)(m0 + m) * lda + k0 + k];
            As[k][m] = v;
        }
        #pragma unroll
        for (int e = tid; e < 16 * 64; e += 256) {
            int k = e >> 6, n = e & 63;
            float v = 0.f;
            if (n0 + n < N) v = W[(long)(k0 + k) * N + n0 + n];
            Ws[k][n] = v;
        }
        __syncthreads();
        #pragma unroll
        for (int kk = 0; kk < 16; kk++) {
            float a[4], w[4];
            #pragma unroll
            for (int i = 0; i < 4; i++) a[i] = As[kk][ty * 4 + i];
            #pragma unroll
            for (int j = 0; j < 4; j++) w[j] = Ws[kk][tx * 4 + j];
            #pragma unroll
            for (int i = 0; i < 4; i++)
                #pragma unroll
                for (int j = 0; j < 4; j++)
                    acc[i][j] += a[i] * w[j];
        }
        __syncthreads();
    }
    #pragma unroll
    for (int i = 0; i < 4; i++) {
        int m = m0 + ty * 4 + i;
        if (m >= M) continue;
        #pragma unroll
        for (int j = 0; j < 4; j++) {
            int n = n0 + tx * 4 + j;
            if (n >= N) continue;
            float v = acc[i][j] + bias[n];
            if (DO_GELU) v = gelu_f(v);
            C[(long)m * N + n] = v;
        }
    }
}

// ---------------------------------------------------------------------------
// h = gelu(layernorm(X)) + pe ; also bf16 copy hb  (runs once)
// ---------------------------------------------------------------------------
__global__ __launch_bounds__(256)
void ln_gelu_pos_k(const float* __restrict__ X,
                   const float* __restrict__ g,
                   const float* __restrict__ be,
                   float* __restrict__ Hout,
                   __hip_bfloat16* __restrict__ Hb) {
    const int row = blockIdx.x;
    const int s = row & (S_ - 1);
    const int t = threadIdx.x;
    const float* x = X + (long)row * D_;
    float v0 = x[t], v1 = x[t + 256];
    __shared__ float red[256];
    red[t] = v0 + v1;
    __syncthreads();
    for (int off = 128; off; off >>= 1) {
        if (t < off) red[t] += red[t + off];
        __syncthreads();
    }
    float mu = red[0] * (1.0f / D_);
    __syncthreads();
    float d0 = v0 - mu, d1 = v1 - mu;
    red[t] = d0 * d0 + d1 * d1;
    __syncthreads();
    for (int off = 128; off; off >>= 1) {
        if (t < off) red[t] += red[t + off];
        __syncthreads();
    }
    float var = red[0] * (1.0f / D_);
    float inv = 1.0f / sqrtf(var + 1e-5f);
    float o0 = gelu_f(d0 * inv * g[t] + be[t]);
    float o1 = gelu_f(d1 * inv * g[t + 256] + be[t + 256]);
    {
        int d = t, i = d >> 1;
        float dv = expf((float)(2 * i) * (-9.210340371976184f / 512.0f));
        float ang = (float)s * dv;
        o0 += (d & 1) ? cosf(ang) : sinf(ang);
    }
    {
        int d = t + 256, i = d >> 1;
        float dv = expf((float)(2 * i) * (-9.210340371976184f / 512.0f));
        float ang = (float)s * dv;
        o1 += (d & 1) ? cosf(ang) : sinf(ang);
    }
    Hout[(long)row * D_ + t] = o0;
    Hout[(long)row * D_ + t + 256] = o1;
    Hb[(long)row * D_ + t] = __float2bfloat16(o0);
    Hb[(long)row * D_ + t + 256] = __float2bfloat16(o1);
}

// ---------------------------------------------------------------------------
// MFMA flash attention (verified structure, unchanged)
// ---------------------------------------------------------------------------
#define LDT 72
__global__ __launch_bounds__(256)
void attn_mfma_k(const __hip_bfloat16* __restrict__ qkv,
                 __hip_bfloat16* __restrict__ O) {
    const int qt = blockIdx.x;
    const int bh = blockIdx.y;
    const int b = bh >> 3, h = bh & (H_ - 1);
    const int tid = threadIdx.x;
    const int wave = tid >> 6, lane = tid & 63;
    const int ln = lane & 15, quad = lane >> 4;
    const int wm = wave * 32;
    const int i0 = qt * 128;

    __shared__ unsigned short Qs[128 * LDT];
    __shared__ unsigned short Ks[64 * LDT];
    __shared__ unsigned short Vt[64 * LDT];
    __shared__ unsigned short Ps[128 * LDT];
    __shared__ float stat[128];

    const unsigned short* base = (const unsigned short*)qkv + (long)b * S_ * (3 * D_);

    {
        const int r0 = tid >> 3, c0 = (tid & 7) * 8;
        #pragma unroll
        for (int i = 0; i < 4; i++) {
            const int rw = i * 32 + r0;
            *(short8*)&Qs[rw * LDT + c0] =
                *(const short8*)(base + (long)(i0 + rw) * (3 * D_) + h * HD_ + c0);
        }
    }

    float m_i[2] = { -INFINITY, -INFINITY };
    float l_i[2] = { 0.f, 0.f };
    floatx4 o_acc[2][4];
    #pragma unroll
    for (int i = 0; i < 2; i++)
        #pragma unroll
        for (int j = 0; j < 4; j++) o_acc[i][j] = (floatx4)0.f;

    const int kr = tid >> 2, kc = (tid & 3) * 16;
    const int vj = tid & 63, vc = (tid >> 6) * 16;

    const int ktmax = 2 * qt + 1;
    for (int kt = 0; kt <= ktmax; kt++) {
        const int j0 = kt * 64;
        {
            const unsigned short* kp = base + (long)(j0 + kr) * (3 * D_) + D_ + h * HD_ + kc;
            *(short8*)&Ks[kr * LDT + kc]     = *(const short8*)(kp);
            *(short8*)&Ks[kr * LDT + kc + 8] = *(const short8*)(kp + 8);
            const unsigned short* vp = base + (long)(j0 + vj) * (3 * D_) + 2 * D_ + h * HD_ + vc;
            short8 v0 = *(const short8*)(vp);
            short8 v1 = *(const short8*)(vp + 8);
            #pragma unroll
            for (int e = 0; e < 8; e++) {
                Vt[(vc + e) * LDT + vj]     = (unsigned short)v0[e];
                Vt[(vc + 8 + e) * LDT + vj] = (unsigned short)v1[e];
            }
        }
        __syncthreads();

        floatx4 sa[4][2];
        #pragma unroll
        for (int mt = 0; mt < 4; mt++)
            #pragma unroll
            for (int nt = 0; nt < 2; nt++) sa[mt][nt] = (floatx4)0.f;
        #pragma unroll
        for (int c = 0; c < 2; c++) {
            short8 kf[4], qf[2];
            #pragma unroll
            for (int mt = 0; mt < 4; mt++)
                kf[mt] = *(const short8*)&Ks[(mt * 16 + ln) * LDT + c * 32 + quad * 8];
            #pragma unroll
            for (int nt = 0; nt < 2; nt++)
                qf[nt] = *(const short8*)&Qs[(wm + nt * 16 + ln) * LDT + c * 32 + quad * 8];
            #pragma unroll
            for (int mt = 0; mt < 4; mt++)
                #pragma unroll
                for (int nt = 0; nt < 2; nt++)
                    sa[mt][nt] = __builtin_amdgcn_mfma_f32_16x16x32_bf16(
                        kf[mt], qf[nt], sa[mt][nt], 0, 0, 0);
        }

        const bool domask = (kt >= 2 * qt);
        #pragma unroll
        for (int nt = 0; nt < 2; nt++) {
            const int qg = i0 + wm + nt * 16 + ln;
            float mx = -INFINITY;
            #pragma unroll
            for (int mt = 0; mt < 4; mt++)
                #pragma unroll
                for (int rg = 0; rg < 4; rg++) {
                    float v = sa[mt][nt][rg] * 0.125f;
                    if (domask && (j0 + mt * 16 + quad * 4 + rg > qg)) v = -INFINITY;
                    sa[mt][nt][rg] = v;
                    mx = fmaxf(mx, v);
                }
            mx = fmaxf(mx, __shfl_xor(mx, 16));
            mx = fmaxf(mx, __shfl_xor(mx, 32));
            const float mn = fmaxf(m_i[nt], mx);
            const float alpha = __expf(m_i[nt] - mn);
            m_i[nt] = mn;
            float ls = 0.f;
            #pragma unroll
            for (int mt = 0; mt < 4; mt++) {
                ushort4 pk;
                float p0 = __expf(sa[mt][nt][0] - mn);
                float p1 = __expf(sa[mt][nt][1] - mn);
                float p2 = __expf(sa[mt][nt][2] - mn);
                float p3 = __expf(sa[mt][nt][3] - mn);
                ls += p0 + p1 + p2 + p3;
                pk.x = f2bf(p0); pk.y = f2bf(p1); pk.z = f2bf(p2); pk.w = f2bf(p3);
                *(ushort4*)&Ps[(wm + nt * 16 + ln) * LDT + mt * 16 + quad * 4] = pk;
            }
            ls += __shfl_xor(ls, 16);
            ls += __shfl_xor(ls, 32);
            l_i[nt] = l_i[nt] * alpha + ls;
            if (quad == 0) stat[wm + nt * 16 + ln] = alpha;
        }

        #pragma unroll
        for (int mt2 = 0; mt2 < 2; mt2++) {
            #pragma unroll
            for (int rg = 0; rg < 4; rg++) {
                const float a = stat[wm + mt2 * 16 + quad * 4 + rg];
                #pragma unroll
                for (int nt = 0; nt < 4; nt++) o_acc[mt2][nt][rg] *= a;
            }
        }

        #pragma unroll
        for (int c = 0; c < 2; c++) {
            short8 pf[2], vf[4];
            #pragma unroll
            for (int mt2 = 0; mt2 < 2; mt2++)
                pf[mt2] = *(const short8*)&Ps[(wm + mt2 * 16 + ln) * LDT + c * 32 + quad * 8];
            #pragma unroll
            for (int nt = 0; nt < 4; nt++)
                vf[nt] = *(const short8*)&Vt[(nt * 16 + ln) * LDT + c * 32 + quad * 8];
            #pragma unroll
            for (int mt2 = 0; mt2 < 2; mt2++)
                #pragma unroll
                for (int nt = 0; nt < 4; nt++)
                    o_acc[mt2][nt] = __builtin_amdgcn_mfma_f32_16x16x32_bf16(
                        pf[mt2], vf[nt], o_acc[mt2][nt], 0, 0, 0);
        }
        __syncthreads();
    }

    if (quad == 0) {
        stat[wm + ln]      = l_i[0];
        stat[wm + 16 + ln] = l_i[1];
    }
    unsigned short* Og = (unsigned short*)O;
    #pragma unroll
    for (int mt2 = 0; mt2 < 2; mt2++) {
        #pragma unroll
        for (int rg = 0; rg < 4; rg++) {
            const float linv = 1.0f / stat[wm + mt2 * 16 + quad * 4 + rg];
            const long row = (long)(b * S_ + i0 + wm + mt2 * 16 + quad * 4 + rg);
            #pragma unroll
            for (int nt = 0; nt < 4; nt++)
                Og[row * D_ + h * HD_ + nt * 16 + ln] =
                    f2bf(o_acc[mt2][nt][rg] * linv);
        }
    }
}

// ---------------------------------------------------------------------------
// Head kernels
// ---------------------------------------------------------------------------
__global__ __launch_bounds__(256)
void head1_k(const float* __restrict__ h, const float* __restrict__ w1,
             const float* __restrict__ b1, float* __restrict__ th) {
    __shared__ float hs[D_];
    const int b = blockIdx.x, n = threadIdx.x;
    const float* hr = h + (long)(b * S_ + S_ - 1) * D_;
    hs[n] = hr[n];
    hs[n + 256] = hr[n + 256];
    __syncthreads();
    float s = 0.f;
    #pragma unroll 8
    for (int k = 0; k < D_; k++) s += hs[k] * w1[(long)k * 256 + n];
    th[b * 256 + n] = gelu_f(s + b1[n]);
}

__global__ __launch_bounds__(64)
void head2_k(const float* __restrict__ th, const float* __restrict__ w2,
             const float* __restrict__ b2, float* __restrict__ out) {
    const int b = blockIdx.x, lane = threadIdx.x;
    const float* t = th + b * 256;
    float s0 = 0.f, s1 = 0.f, s2 = 0.f;
    #pragma unroll
    for (int e = 0; e < 4; e++) {
        const int k = lane * 4 + e;
        const float tv = t[k];
        s0 += tv * w2[k * 3 + 0];
        s1 += tv * w2[k * 3 + 1];
        s2 += tv * w2[k * 3 + 2];
    }
    #pragma unroll
    for (int off = 1; off < 64; off <<= 1) {
        s0 += __shfl_xor(s0, off);
        s1 += __shfl_xor(s1, off);
        s2 += __shfl_xor(s2, off);
    }
    if (lane == 0) {
        out[b * 3 + 0] = s0 + b2[0];
        out[b * 3 + 1] = s1 + b2[1];
        out[b * 3 + 2] = s2 + b2[2];
    }
}

// ---------------------------------------------------------------------------
extern "C" void kernel_launch(void* const* d_in, const int* in_sizes, int n_in,
                              void* d_out, int out_size, void* d_ws, size_t ws_size,
                              hipStream_t stream) {
    const float* x     = (const float*)d_in[0];
    const float* w_in  = (const float*)d_in[1];
    const float* b_in  = (const float*)d_in[2];
    const float* g_in  = (const float*)d_in[3];
    const float* be_in = (const float*)d_in[4];
    const float* w_qkv = (const float*)d_in[5];
    const float* b_qkv = (const float*)d_in[6];
    const float* w_out = (const float*)d_in[7];
    const float* b_out = (const float*)d_in[8];
    const float* g1    = (const float*)d_in[9];
    const float* be1   = (const float*)d_in[10];
    const float* w_ff1 = (const float*)d_in[11];
    const float* b_ff1 = (const float*)d_in[12];
    const float* w_ff2 = (const float*)d_in[13];
    const float* b_ff2 = (const float*)d_in[14];
    const float* g2    = (const float*)d_in[15];
    const float* be2   = (const float*)d_in[16];
    const float* w_h1  = (const float*)d_in[17];
    const float* b_h1  = (const float*)d_in[18];
    const float* w_h2  = (const float*)d_in[19];
    const float* b_h2  = (const float*)d_in[20];
    float* out = (float*)d_out;

    float* h    = (float*)d_ws;
    float* bufB = h + (long)M_ * D_;
    float* th   = bufB + (long)M_ * D_;
    __hip_bfloat16* hb    = (__hip_bfloat16*)(th + 32 * 256);
    __hip_bfloat16* attb  = hb + (long)M_ * D_;
    __hip_bfloat16* bufAb = attb + (long)M_ * D_;
    __hip_bfloat16* qkvT  = bufAb + (long)M_ * FF_;
    __hip_bfloat16* outT  = qkvT + (long)L_ * (3 * D_) * D_;
    __hip_bfloat16* ff1T  = outT + (long)L_ * D_ * D_;
    __hip_bfloat16* ff2T  = ff1T + (long)L_ * FF_ * D_;

    dim3 blk(16, 16);

    transpose_cast_k<<<dim3((3 * D_) / 32, D_ / 32, L_), 256, 0, stream>>>(w_qkv, qkvT, D_, 3 * D_);
    transpose_cast_k<<<dim3(D_ / 32, D_ / 32, L_), 256, 0, stream>>>(w_out, outT, D_, D_);
    transpose_cast_k<<<dim3(FF_ / 32, D_ / 32, L_), 256, 0, stream>>>(w_ff1, ff1T, D_, FF_);
    transpose_cast_k<<<dim3(D_ / 32, FF_ / 32, L_), 256, 0, stream>>>(w_ff2, ff2T, FF_, D_);

    gemm_bias_k<0><<<dim3(D_ / 64, M_ / 64), blk, 0, stream>>>(
        x, IN_, w_in, b_in, bufB, M_, D_, IN_);
    ln_gelu_pos_k<<<M_, 256, 0, stream>>>(bufB, g_in, be_in, h, hb);

    for (int l = 0; l < L_; l++) {
        // qkv -> bf16 bufAb (128^2 counted-vmcnt, 1536 blocks)
        gemm_mfma_k<0, 1, 0><<<dim3((3 * D_) / 128, M_ / 128), 256, 0, stream>>>(
            hb, qkvT + (long)l * (3 * D_) * D_, b_qkv + l * 3 * D_, nullptr,
            bufAb, 3 * D_, D_);
        attn_mfma_k<<<dim3(S_ / 128, B_ * H_), 256, 0, stream>>>(bufAb, attb);
        // fused: h = LN(attb @ outT + b_out + h)  (writes h fp32 + hb bf16)
        gemm_ln_k<<<256, 512, 0, stream>>>(
            attb, outT + (long)l * D_ * D_, b_out + l * D_, h,
            g1 + l * D_, be1 + l * D_, h, hb, D_);
        // ff1 -> bf16 bufAb (gelu)  (128^2 counted-vmcnt, 2048 blocks, 2/CU)
        gemm_mfma_k<1, 1, 0><<<dim3(FF_ / 128, M_ / 128), 256, 0, stream>>>(
            hb, ff1T + (long)l * FF_ * D_, b_ff1 + l * FF_, nullptr,
            bufAb, FF_, D_);
        // fused: h = LN(bufAb @ ff2T + b_ff2 + h)
        gemm_ln_k<<<256, 512, 0, stream>>>(
            bufAb, ff2T + (long)l * D_ * FF_, b_ff2 + l * D_, h,
            g2 + l * D_, be2 + l * D_, h, hb, FF_);
    }

    head1_k<<<B_, 256, 0, stream>>>(h, w_h1, b_h1, th);
    head2_k<<<B_, 64, 0, stream>>>(th, w_h2, b_h2, out);
}